// Round 5
// baseline (482.741 us; speedup 1.0000x reference)
//
#include <hip/hip_runtime.h>
#include <hip/hip_bf16.h>
#include <math.h>

typedef __hip_bfloat16 bf16;
typedef __attribute__((ext_vector_type(8))) __bf16 bf16x8;
typedef __attribute__((ext_vector_type(4))) float f32x4;

#define KIN 512
#define F1  256
#define F2  16
#define F3  40

// ---------------- helpers ----------------

__device__ inline unsigned pk_bf2(float a, float b) {
  bf16 x = __float2bfloat16(a), y = __float2bfloat16(b);
  unsigned short ux = *(unsigned short*)&x, uy = *(unsigned short*)&y;
  return (unsigned)ux | ((unsigned)uy << 16);
}
__device__ inline float bfbits(unsigned u16) {
  unsigned v = u16 << 16;
  return *(float*)&v;
}
__device__ inline void async16(const void* g, void* l) {
  __builtin_amdgcn_global_load_lds((const __attribute__((address_space(1))) void*)g,
                                   (__attribute__((address_space(3))) void*)l, 16, 0, 0);
}
__device__ inline void accum8(float* acc, uint4 h, float w) {
  acc[0] = fmaf(w, bfbits(h.x & 0xffff), acc[0]);
  acc[1] = fmaf(w, bfbits(h.x >> 16),    acc[1]);
  acc[2] = fmaf(w, bfbits(h.y & 0xffff), acc[2]);
  acc[3] = fmaf(w, bfbits(h.y >> 16),    acc[3]);
  acc[4] = fmaf(w, bfbits(h.z & 0xffff), acc[4]);
  acc[5] = fmaf(w, bfbits(h.z >> 16),    acc[5]);
  acc[6] = fmaf(w, bfbits(h.w & 0xffff), acc[6]);
  acc[7] = fmaf(w, bfbits(h.w >> 16),    acc[7]);
}

// ---------------- init: zero cnt/fill + flag + W1 transpose (fused) --------

__global__ __launch_bounds__(256) void k_init2(int* __restrict__ cnt, int* __restrict__ fill,
                                               const int* __restrict__ ei, int* __restrict__ flag,
                                               const float* __restrict__ W,
                                               unsigned short* __restrict__ Wt,
                                               int n, int nb) {
  int b = blockIdx.x;
  int t = threadIdx.x;
  if (b < nb) {
    int i = b * 256 + t;
    if (i < n) { cnt[i] = 0; fill[i] = 0; }
    if (b == 0 && t == 0)
      *flag = (ei[1] == 0 && ei[3] == 0 && ei[5] == 0 && ei[7] == 0) ? 1 : 0;
  } else {
    __shared__ float tile[32][33];
    int b2 = b - nb;
    int k0 = (b2 & 15) * 32;   // K dim (512/32=16)
    int n0 = (b2 >> 4) * 32;   // N dim (256/32=8)
    int lr = t >> 5, lc = t & 31;
#pragma unroll
    for (int rr = 0; rr < 32; rr += 8)
      tile[lr + rr][lc] = W[(size_t)(k0 + lr + rr) * F1 + n0 + lc];
    __syncthreads();
#pragma unroll
    for (int rr = 0; rr < 32; rr += 8) {
      bf16 v = __float2bfloat16(tile[lc][lr + rr]);
      Wt[(size_t)(n0 + lr + rr) * KIN + k0 + lc] = *(unsigned short*)&v;
    }
  }
}

__global__ void k_count(const int* __restrict__ ei, const int* __restrict__ flag,
                        int* __restrict__ cnt, int E) {
  int e = blockIdx.x * 256 + threadIdx.x;
  if (e >= E) return;
  int is64 = *flag;
  int d = is64 ? ei[2 * E + 2 * e] : ei[E + e];
  atomicAdd(&cnt[d], 1);
}

__global__ __launch_bounds__(256) void k_scan1(const int* __restrict__ cnt,
                                               int* __restrict__ off,
                                               int* __restrict__ bsum,
                                               float* __restrict__ dinv, int N) {
  __shared__ int s[256];
  int t = threadIdx.x;
  int base = blockIdx.x * 1024 + t * 4;
  int v0 = (base + 0 < N) ? cnt[base + 0] : 0;
  int v1 = (base + 1 < N) ? cnt[base + 1] : 0;
  int v2 = (base + 2 < N) ? cnt[base + 2] : 0;
  int v3 = (base + 3 < N) ? cnt[base + 3] : 0;
  if (base + 0 < N) dinv[base + 0] = rsqrtf((float)(v0 + 1));
  if (base + 1 < N) dinv[base + 1] = rsqrtf((float)(v1 + 1));
  if (base + 2 < N) dinv[base + 2] = rsqrtf((float)(v2 + 1));
  if (base + 3 < N) dinv[base + 3] = rsqrtf((float)(v3 + 1));
  int tsum = v0 + v1 + v2 + v3;
  s[t] = tsum;
  __syncthreads();
  for (int d = 1; d < 256; d <<= 1) {
    int u = (t >= d) ? s[t - d] : 0;
    __syncthreads();
    s[t] += u;
    __syncthreads();
  }
  int excl = s[t] - tsum;
  int p0 = excl + v0, p1 = p0 + v1, p2 = p1 + v2, p3 = p2 + v3;
  if (base + 0 < N) off[base + 1] = p0;
  if (base + 1 < N) off[base + 2] = p1;
  if (base + 2 < N) off[base + 3] = p2;
  if (base + 3 < N) off[base + 4] = p3;
  if (t == 255) bsum[blockIdx.x] = s[255];
}

__global__ void k_scan2(const int* __restrict__ bsum, int* __restrict__ carry, int nb) {
  int t = threadIdx.x;
  int v = (t < nb) ? bsum[t] : 0;
  int incl = v;
  for (int d = 1; d < 64; d <<= 1) {
    int u = __shfl_up(incl, d, 64);
    if (t >= d) incl += u;
  }
  if (t < nb) carry[t] = incl - v;
}

__global__ __launch_bounds__(256) void k_scan3(int* __restrict__ off,
                                               const int* __restrict__ carry, int N) {
  int t = threadIdx.x;
  int c = carry[blockIdx.x];
  int base = blockIdx.x * 1024 + t * 4;
#pragma unroll
  for (int k = 0; k < 4; ++k)
    if (base + k < N) off[base + k + 1] += c;
  if (blockIdx.x == 0 && t == 0) off[0] = 0;
}

__global__ void k_scatter(const int* __restrict__ ei, const int* __restrict__ flag,
                          const int* __restrict__ off, int* __restrict__ fill,
                          const float* __restrict__ dinv,
                          int* __restrict__ csrc, float* __restrict__ cw, int E) {
  int e = blockIdx.x * 256 + threadIdx.x;
  if (e >= E) return;
  int is64 = *flag;
  int s, d;
  if (is64) { s = ei[2 * e]; d = ei[2 * E + 2 * e]; }
  else      { s = ei[e];     d = ei[E + e]; }
  int pos = off[d] + atomicAdd(&fill[d], 1);
  csrc[pos] = s;
  cw[pos] = dinv[s] * dinv[d];
}

// ---------------- GEMM1: h1 = bf16(x) @ W1, A-direct + B-dbuf MFMA ---------
// Tile 64(M) x 256(N), 4 waves; wave w -> cols [w*64, w*64+64).
// A: direct global f32 loads (L1-shared across waves), packed to bf16 in VGPRs.
// B: double-buffered LDS via global_load_lds; prefetch k+1 before compute(k).

__global__ __launch_bounds__(256) void k_gemm1(const float* __restrict__ A,
                                               const unsigned short* __restrict__ Bt,
                                               bf16* __restrict__ C, int M) {
  __shared__ unsigned short Bs[2][256 * 32];   // 2 x 16 KB
  int t = threadIdx.x;
  int wave = t >> 6, lane = t & 63;
  int row0 = blockIdx.x * 64;
  int q = lane >> 4, m16 = lane & 15;
  int brow_l = lane >> 2, bchk_p = lane & 3;

  // A row pointers for the 4 m-frags (clamped)
  const float* pa[4];
#pragma unroll
  for (int i = 0; i < 4; ++i) {
    int r = row0 + i * 16 + m16;
    if (r >= M) r = M - 1;
    pa[i] = A + (size_t)r * KIN + q * 8;
  }

  f32x4 acc[4][4];
#pragma unroll
  for (int i = 0; i < 4; ++i)
#pragma unroll
    for (int j = 0; j < 4; ++j) acc[i][j] = {0.f, 0.f, 0.f, 0.f};

  // stage B slice kb into buffer buf
  auto stageB = [&](int kb, int buf) {
#pragma unroll
    for (int j = 0; j < 4; ++j) {
      int nr = wave * 64 + j * 16;
      int row = nr + brow_l;
      int gchk = bchk_p ^ ((row >> 1) & 3);
      const unsigned short* gp = Bt + (size_t)row * KIN + kb * 32 + gchk * 8;
      async16(gp, &Bs[buf][nr * 32]);
    }
  };

  stageB(0, 0);
  __syncthreads();

  for (int kb = 0; kb < 16; ++kb) {
    int cur = kb & 1;
    if (kb < 15) stageB(kb + 1, cur ^ 1);   // prefetch overlaps compute below
    // A: 4 frags direct from global, pack f32->bf16
    bf16x8 af[4];
#pragma unroll
    for (int i = 0; i < 4; ++i) {
      float4 f0 = *(const float4*)(pa[i] + kb * 32);
      float4 f1 = *(const float4*)(pa[i] + kb * 32 + 4);
      uint4 pk;
      pk.x = pk_bf2(f0.x, f0.y); pk.y = pk_bf2(f0.z, f0.w);
      pk.z = pk_bf2(f1.x, f1.y); pk.w = pk_bf2(f1.z, f1.w);
      af[i] = *(bf16x8*)&pk;
    }
    // B: 4 n-frags from LDS (proven swizzle), 16 MFMA
#pragma unroll
    for (int j = 0; j < 4; ++j) {
      int nloc = wave * 64 + j * 16 + m16;
      bf16x8 b = *(const bf16x8*)(&Bs[cur][nloc * 32] + ((q ^ ((nloc >> 1) & 3)) * 8));
#pragma unroll
      for (int i = 0; i < 4; ++i)
        acc[i][j] = __builtin_amdgcn_mfma_f32_16x16x32_bf16(af[i], b, acc[i][j], 0, 0, 0);
    }
    __syncthreads();   // drains prefetch (mostly landed during MFMAs), gates swap
  }

  // epilogue: D[row=(lane>>4)*4+r][col=lane&15]
#pragma unroll
  for (int i = 0; i < 4; ++i) {
#pragma unroll
    for (int r = 0; r < 4; ++r) {
      int row = row0 + i * 16 + q * 4 + r;
      if (row < M) {
#pragma unroll
        for (int j = 0; j < 4; ++j) {
          int col = wave * 64 + j * 16 + m16;
          C[(size_t)row * F1 + col] = __float2bfloat16(acc[i][j][r]);
        }
      }
    }
  }
}

// ---------------- agg1 + bias + relu + GEMM2 fused: h2 = relu(agg(h1)+b1)@W2
// 8 nodes/block, 32 lanes/node, lane owns 8 feats. W2 LDS-transposed [c][k].

__global__ __launch_bounds__(256) void k_agg1_g2(const bf16* __restrict__ H,
                                                 const int* __restrict__ off,
                                                 const int* __restrict__ csrc,
                                                 const float* __restrict__ cw,
                                                 const float* __restrict__ dinv,
                                                 const float* __restrict__ b1,
                                                 const float* __restrict__ W2,
                                                 float* __restrict__ h2, int N) {
  __shared__ float W2t[16 * 257];   // [c][k], stride 257 breaks conflicts
  int t = threadIdx.x;
  // stage W2 transposed
#pragma unroll
  for (int m = 0; m < 16; ++m) {
    int idx = m * 256 + t;          // idx = k*16 + c
    int k = idx >> 4, c = idx & 15;
    W2t[c * 257 + k] = W2[idx];
  }
  __syncthreads();

  int i = blockIdx.x * 8 + (t >> 5);
  if (i >= N) return;
  int l = t & 31;
  int f0 = l * 8;
  const unsigned short* Hu = (const unsigned short*)H;
  float di = dinv[i];
  float w0 = di * di;
  float acc[8];
  {
    uint4 h = *(const uint4*)(Hu + (size_t)i * F1 + f0);
    acc[0] = w0 * bfbits(h.x & 0xffff); acc[1] = w0 * bfbits(h.x >> 16);
    acc[2] = w0 * bfbits(h.y & 0xffff); acc[3] = w0 * bfbits(h.y >> 16);
    acc[4] = w0 * bfbits(h.z & 0xffff); acc[5] = w0 * bfbits(h.z >> 16);
    acc[6] = w0 * bfbits(h.w & 0xffff); acc[7] = w0 * bfbits(h.w >> 16);
  }
  int e = off[i], e1 = off[i + 1];
  for (; e + 4 <= e1; e += 4) {
    int s0 = csrc[e + 0], s1 = csrc[e + 1], s2 = csrc[e + 2], s3 = csrc[e + 3];
    float wa = cw[e + 0], wb = cw[e + 1], wc = cw[e + 2], wd = cw[e + 3];
    uint4 g0 = *(const uint4*)(Hu + (size_t)s0 * F1 + f0);
    uint4 g1 = *(const uint4*)(Hu + (size_t)s1 * F1 + f0);
    uint4 g2 = *(const uint4*)(Hu + (size_t)s2 * F1 + f0);
    uint4 g3 = *(const uint4*)(Hu + (size_t)s3 * F1 + f0);
    accum8(acc, g0, wa);
    accum8(acc, g1, wb);
    accum8(acc, g2, wc);
    accum8(acc, g3, wd);
  }
  for (; e < e1; ++e) {
    int s = csrc[e];
    float w = cw[e];
    uint4 g = *(const uint4*)(Hu + (size_t)s * F1 + f0);
    accum8(acc, g, w);
  }
  // bias + relu -> vout (out1 row slice, kept in registers)
  float4 bb0 = *(const float4*)(b1 + f0);
  float4 bb1 = *(const float4*)(b1 + f0 + 4);
  float vout[8] = {
    fmaxf(acc[0] + bb0.x, 0.f), fmaxf(acc[1] + bb0.y, 0.f),
    fmaxf(acc[2] + bb0.z, 0.f), fmaxf(acc[3] + bb0.w, 0.f),
    fmaxf(acc[4] + bb1.x, 0.f), fmaxf(acc[5] + bb1.y, 0.f),
    fmaxf(acc[6] + bb1.z, 0.f), fmaxf(acc[7] + bb1.w, 0.f)};
  // per-lane partial dot with W2 (k in [f0, f0+8))
  float p[16];
#pragma unroll
  for (int c = 0; c < 16; ++c) {
    const float* wr = &W2t[c * 257 + f0];
    float4 wa = *(const float4*)wr;
    float4 wb = *(const float4*)(wr + 4);
    float s = vout[0] * wa.x + vout[1] * wa.y + vout[2] * wa.z + vout[3] * wa.w;
    s = fmaf(vout[4], wb.x, s); s = fmaf(vout[5], wb.y, s);
    s = fmaf(vout[6], wb.z, s); s = fmaf(vout[7], wb.w, s);
    p[c] = s;
  }
  // reduce across the 32 lanes of this node
#pragma unroll
  for (int d = 1; d < 32; d <<= 1) {
#pragma unroll
    for (int c = 0; c < 16; ++c) p[c] += __shfl_xor(p[c], d);
  }
  if (l < 16) {
    float outv = 0.f;
#pragma unroll
    for (int c = 0; c < 16; ++c) outv = (l == c) ? p[c] : outv;
    h2[(size_t)i * F2 + l] = outv;
  }
}

// ---------------- Aggregation, 16 features (layer 2): out2=relu(agg(h2)+b2) -

__global__ __launch_bounds__(256) void k_agg16(const float* __restrict__ H,
                                               const int* __restrict__ off,
                                               const int* __restrict__ csrc,
                                               const float* __restrict__ cw,
                                               const float* __restrict__ dinv,
                                               const float* __restrict__ bias,
                                               float* __restrict__ O, int N) {
  int t = threadIdx.x;
  int i = blockIdx.x * 16 + (t >> 4);
  int f = t & 15;
  if (i >= N) return;
  float di = dinv[i];
  float acc = di * di * H[(size_t)i * F2 + f];
  int e = off[i], e1 = off[i + 1];
  for (; e + 4 <= e1; e += 4) {
    int s0 = csrc[e + 0], s1 = csrc[e + 1], s2 = csrc[e + 2], s3 = csrc[e + 3];
    float wa = cw[e + 0], wb = cw[e + 1], wc = cw[e + 2], wd = cw[e + 3];
    float g0 = H[(size_t)s0 * F2 + f];
    float g1 = H[(size_t)s1 * F2 + f];
    float g2 = H[(size_t)s2 * F2 + f];
    float g3 = H[(size_t)s3 * F2 + f];
    acc = fmaf(wa, g0, acc);
    acc = fmaf(wb, g1, acc);
    acc = fmaf(wc, g2, acc);
    acc = fmaf(wd, g3, acc);
  }
  for (; e < e1; ++e)
    acc = fmaf(cw[e], H[(size_t)csrc[e] * F2 + f], acc);
  acc = fmaxf(acc + bias[f], 0.f);
  O[(size_t)i * F2 + f] = acc;
}

// ---------------- agg(out2) + GEMM3 + bias + log_softmax fused -------------
// 16 nodes/block, 16 lanes/node; lane f handles out cols {f, f+16, f+32}.

__global__ __launch_bounds__(256) void k_agg3_g3(const float* __restrict__ H,
                                                 const int* __restrict__ off,
                                                 const int* __restrict__ csrc,
                                                 const float* __restrict__ cw,
                                                 const float* __restrict__ dinv,
                                                 const float* __restrict__ W3,
                                                 const float* __restrict__ b3,
                                                 float* __restrict__ O, int N) {
  __shared__ float W3s[F2 * F3];          // 640 floats
  __shared__ float b3s[F3];
  __shared__ float aggs[16 * 17];         // [node][k], stride 17
  int t = threadIdx.x;
  for (int idx = t; idx < F2 * F3; idx += 256) W3s[idx] = W3[idx];
  if (t < F3) b3s[t] = b3[t];
  __syncthreads();

  int node = t >> 4, f = t & 15;
  int i = blockIdx.x * 16 + node;
  if (i >= N) return;
  float di = dinv[i];
  float acc = di * di * H[(size_t)i * F2 + f];
  int e = off[i], e1 = off[i + 1];
  for (; e + 4 <= e1; e += 4) {
    int s0 = csrc[e + 0], s1 = csrc[e + 1], s2 = csrc[e + 2], s3 = csrc[e + 3];
    float wa = cw[e + 0], wb = cw[e + 1], wc = cw[e + 2], wd = cw[e + 3];
    float g0 = H[(size_t)s0 * F2 + f];
    float g1 = H[(size_t)s1 * F2 + f];
    float g2 = H[(size_t)s2 * F2 + f];
    float g3 = H[(size_t)s3 * F2 + f];
    acc = fmaf(wa, g0, acc);
    acc = fmaf(wb, g1, acc);
    acc = fmaf(wc, g2, acc);
    acc = fmaf(wd, g3, acc);
  }
  for (; e < e1; ++e)
    acc = fmaf(cw[e], H[(size_t)csrc[e] * F2 + f], acc);
  aggs[node * 17 + f] = acc;   // same-wave produce/consume; lgkmcnt ordering

  // gemm3: 3 output cols per lane
  const float* ar = &aggs[node * 17];
  float o0 = b3s[f], o1 = b3s[f + 16], o2 = (f < 8) ? b3s[f + 32] : 0.f;
#pragma unroll
  for (int k = 0; k < F2; ++k) {
    float a = ar[k];
    o0 = fmaf(a, W3s[k * F3 + f], o0);
    o1 = fmaf(a, W3s[k * F3 + f + 16], o1);
    if (f < 8) o2 = fmaf(a, W3s[k * F3 + f + 32], o2);
  }
  // log_softmax across 40 cols (16-lane subgroup reduce)
  float m = fmaxf(o0, o1);
  if (f < 8) m = fmaxf(m, o2);
#pragma unroll
  for (int d = 1; d < 16; d <<= 1) m = fmaxf(m, __shfl_xor(m, d, 16));
  float s = __expf(o0 - m) + __expf(o1 - m) + ((f < 8) ? __expf(o2 - m) : 0.f);
#pragma unroll
  for (int d = 1; d < 16; d <<= 1) s += __shfl_xor(s, d, 16);
  float lse = m + __logf(s);
  float* orow = O + (size_t)i * F3;
  orow[f] = o0 - lse;
  orow[f + 16] = o1 - lse;
  if (f < 8) orow[f + 32] = o2 - lse;
}

// ---------------- launch ----------------

extern "C" void kernel_launch(void* const* d_in, const int* in_sizes, int n_in,
                              void* d_out, int out_size, void* d_ws, size_t ws_size,
                              hipStream_t stream) {
  const float* x  = (const float*)d_in[0];
  const int*   ei = (const int*)d_in[1];
  const float* W1 = (const float*)d_in[2];
  const float* b1 = (const float*)d_in[3];
  const float* W2 = (const float*)d_in[4];
  const float* b2 = (const float*)d_in[5];
  const float* W3 = (const float*)d_in[6];
  const float* b3 = (const float*)d_in[7];
  float* out = (float*)d_out;

  int N = in_sizes[0] / KIN;
  int E = in_sizes[1] / 2;

  char* p = (char*)d_ws;
  auto take = [&](size_t bytes) {
    char* r = p;
    p += (bytes + 255) & ~(size_t)255;
    return r;
  };
  int*   flag  = (int*)take(4);
  int*   cnt   = (int*)take((size_t)N * 4);
  int*   fill  = (int*)take((size_t)N * 4);
  int*   off   = (int*)take((size_t)(N + 1) * 4);
  float* dinv  = (float*)take((size_t)N * 4);
  int*   bsum  = (int*)take(64 * 4);
  int*   carry = (int*)take(64 * 4);
  int*   csrc  = (int*)take((size_t)E * 4);
  float* cw    = (float*)take((size_t)E * 4);
  unsigned short* w1t = (unsigned short*)take((size_t)KIN * F1 * 2);
  bf16*  h1    = (bf16*)take((size_t)N * F1 * 2);
  float* h2    = (float*)take((size_t)N * F2 * 4);
  float* out2  = (float*)take((size_t)N * F2 * 4);

  int nb  = (N + 255) / 256;
  int ebk = (E + 255) / 256;
  int nsc = (N + 1023) / 1024;

  k_init2<<<nb + 128, 256, 0, stream>>>(cnt, fill, ei, flag, W1, w1t, N, nb);
  k_count<<<ebk, 256, 0, stream>>>(ei, flag, cnt, E);
  k_scan1<<<nsc, 256, 0, stream>>>(cnt, off, bsum, dinv, N);
  k_scan2<<<1, 64, 0, stream>>>(bsum, carry, nsc);
  k_scan3<<<nsc, 256, 0, stream>>>(off, carry, N);
  k_scatter<<<ebk, 256, 0, stream>>>(ei, flag, off, fill, dinv, csrc, cw, E);

  k_gemm1<<<(N + 63) / 64, 256, 0, stream>>>(x, w1t, h1, N);
  k_agg1_g2<<<(N + 7) / 8, 256, 0, stream>>>(h1, off, csrc, cw, dinv, b1, W2, h2, N);
  k_agg16<<<(N + 15) / 16, 256, 0, stream>>>(h2, off, csrc, cw, dinv, b2, out2, N);
  k_agg3_g3<<<(N + 15) / 16, 256, 0, stream>>>(out2, off, csrc, cw, dinv, W3, b3, out, N);
}

// Round 6
// 436.887 us; speedup vs baseline: 1.1050x; 1.1050x over previous
//
#include <hip/hip_runtime.h>
#include <hip/hip_bf16.h>
#include <math.h>

typedef __hip_bfloat16 bf16;
typedef __attribute__((ext_vector_type(8))) __bf16 bf16x8;
typedef __attribute__((ext_vector_type(4))) float f32x4;

#define KIN 512
#define F1  256
#define F2  16
#define F3  40

// ---------------- helpers ----------------

__device__ inline unsigned pk_bf2(float a, float b) {
  bf16 x = __float2bfloat16(a), y = __float2bfloat16(b);
  unsigned short ux = *(unsigned short*)&x, uy = *(unsigned short*)&y;
  return (unsigned)ux | ((unsigned)uy << 16);
}
__device__ inline float bfbits(unsigned u16) {
  unsigned v = u16 << 16;
  return *(float*)&v;
}
__device__ inline void async16(const void* g, void* l) {
  __builtin_amdgcn_global_load_lds((const __attribute__((address_space(1))) void*)g,
                                   (__attribute__((address_space(3))) void*)l, 16, 0, 0);
}
__device__ inline void accum8(float* acc, uint4 h, float w) {
  acc[0] = fmaf(w, bfbits(h.x & 0xffff), acc[0]);
  acc[1] = fmaf(w, bfbits(h.x >> 16),    acc[1]);
  acc[2] = fmaf(w, bfbits(h.y & 0xffff), acc[2]);
  acc[3] = fmaf(w, bfbits(h.y >> 16),    acc[3]);
  acc[4] = fmaf(w, bfbits(h.z & 0xffff), acc[4]);
  acc[5] = fmaf(w, bfbits(h.z >> 16),    acc[5]);
  acc[6] = fmaf(w, bfbits(h.w & 0xffff), acc[6]);
  acc[7] = fmaf(w, bfbits(h.w >> 16),    acc[7]);
}

// ---------------- init: zero cnt/fill + flag + W1 transpose (fused) --------

__global__ __launch_bounds__(256) void k_init2(int* __restrict__ cnt, int* __restrict__ fill,
                                               const int* __restrict__ ei, int* __restrict__ flag,
                                               const float* __restrict__ W,
                                               unsigned short* __restrict__ Wt,
                                               int n, int nb) {
  int b = blockIdx.x;
  int t = threadIdx.x;
  if (b < nb) {
    int i = b * 256 + t;
    if (i < n) { cnt[i] = 0; fill[i] = 0; }
    if (b == 0 && t == 0)
      *flag = (ei[1] == 0 && ei[3] == 0 && ei[5] == 0 && ei[7] == 0) ? 1 : 0;
  } else {
    __shared__ float tile[32][33];
    int b2 = b - nb;
    int k0 = (b2 & 15) * 32;
    int n0 = (b2 >> 4) * 32;
    int lr = t >> 5, lc = t & 31;
#pragma unroll
    for (int rr = 0; rr < 32; rr += 8)
      tile[lr + rr][lc] = W[(size_t)(k0 + lr + rr) * F1 + n0 + lc];
    __syncthreads();
#pragma unroll
    for (int rr = 0; rr < 32; rr += 8) {
      bf16 v = __float2bfloat16(tile[lc][lr + rr]);
      Wt[(size_t)(n0 + lr + rr) * KIN + k0 + lc] = *(unsigned short*)&v;
    }
  }
}

__global__ void k_count(const int* __restrict__ ei, const int* __restrict__ flag,
                        int* __restrict__ cnt, int E) {
  int e = blockIdx.x * 256 + threadIdx.x;
  if (e >= E) return;
  int is64 = *flag;
  int d = is64 ? ei[2 * E + 2 * e] : ei[E + e];
  atomicAdd(&cnt[d], 1);
}

__global__ __launch_bounds__(256) void k_scan1(const int* __restrict__ cnt,
                                               int* __restrict__ off,
                                               int* __restrict__ bsum,
                                               float* __restrict__ dinv, int N) {
  __shared__ int s[256];
  int t = threadIdx.x;
  int base = blockIdx.x * 1024 + t * 4;
  int v0 = (base + 0 < N) ? cnt[base + 0] : 0;
  int v1 = (base + 1 < N) ? cnt[base + 1] : 0;
  int v2 = (base + 2 < N) ? cnt[base + 2] : 0;
  int v3 = (base + 3 < N) ? cnt[base + 3] : 0;
  if (base + 0 < N) dinv[base + 0] = rsqrtf((float)(v0 + 1));
  if (base + 1 < N) dinv[base + 1] = rsqrtf((float)(v1 + 1));
  if (base + 2 < N) dinv[base + 2] = rsqrtf((float)(v2 + 1));
  if (base + 3 < N) dinv[base + 3] = rsqrtf((float)(v3 + 1));
  int tsum = v0 + v1 + v2 + v3;
  s[t] = tsum;
  __syncthreads();
  for (int d = 1; d < 256; d <<= 1) {
    int u = (t >= d) ? s[t - d] : 0;
    __syncthreads();
    s[t] += u;
    __syncthreads();
  }
  int excl = s[t] - tsum;
  int p0 = excl + v0, p1 = p0 + v1, p2 = p1 + v2, p3 = p2 + v3;
  if (base + 0 < N) off[base + 1] = p0;
  if (base + 1 < N) off[base + 2] = p1;
  if (base + 2 < N) off[base + 3] = p2;
  if (base + 3 < N) off[base + 4] = p3;
  if (t == 255) bsum[blockIdx.x] = s[255];
}

__global__ void k_scan2(const int* __restrict__ bsum, int* __restrict__ carry, int nb) {
  int t = threadIdx.x;
  int v = (t < nb) ? bsum[t] : 0;
  int incl = v;
  for (int d = 1; d < 64; d <<= 1) {
    int u = __shfl_up(incl, d, 64);
    if (t >= d) incl += u;
  }
  if (t < nb) carry[t] = incl - v;
}

__global__ __launch_bounds__(256) void k_scan3(int* __restrict__ off,
                                               const int* __restrict__ carry, int N) {
  int t = threadIdx.x;
  int c = carry[blockIdx.x];
  int base = blockIdx.x * 1024 + t * 4;
#pragma unroll
  for (int k = 0; k < 4; ++k)
    if (base + k < N) off[base + k + 1] += c;
  if (blockIdx.x == 0 && t == 0) off[0] = 0;
}

// edge record: {src, weight_bits} packed -> one 8B scattered store, one 8B stream load
__global__ void k_scatter(const int* __restrict__ ei, const int* __restrict__ flag,
                          const int* __restrict__ off, int* __restrict__ fill,
                          const float* __restrict__ dinv,
                          int2* __restrict__ ew, int E) {
  int e = blockIdx.x * 256 + threadIdx.x;
  if (e >= E) return;
  int is64 = *flag;
  int s, d;
  if (is64) { s = ei[2 * e]; d = ei[2 * E + 2 * e]; }
  else      { s = ei[e];     d = ei[E + e]; }
  int pos = off[d] + atomicAdd(&fill[d], 1);
  float w = dinv[s] * dinv[d];
  ew[pos] = make_int2(s, __float_as_int(w));
}

// ---------------- GEMM1: h1 = bf16(x) @ W1, A-direct + B-dbuf MFMA ---------

__global__ __launch_bounds__(256) void k_gemm1(const float* __restrict__ A,
                                               const unsigned short* __restrict__ Bt,
                                               bf16* __restrict__ C, int M) {
  __shared__ unsigned short Bs[2][256 * 32];
  int t = threadIdx.x;
  int wave = t >> 6, lane = t & 63;
  int row0 = blockIdx.x * 64;
  int q = lane >> 4, m16 = lane & 15;
  int brow_l = lane >> 2, bchk_p = lane & 3;

  const float* pa[4];
#pragma unroll
  for (int i = 0; i < 4; ++i) {
    int r = row0 + i * 16 + m16;
    if (r >= M) r = M - 1;
    pa[i] = A + (size_t)r * KIN + q * 8;
  }

  f32x4 acc[4][4];
#pragma unroll
  for (int i = 0; i < 4; ++i)
#pragma unroll
    for (int j = 0; j < 4; ++j) acc[i][j] = {0.f, 0.f, 0.f, 0.f};

  auto stageB = [&](int kb, int buf) {
#pragma unroll
    for (int j = 0; j < 4; ++j) {
      int nr = wave * 64 + j * 16;
      int row = nr + brow_l;
      int gchk = bchk_p ^ ((row >> 1) & 3);
      const unsigned short* gp = Bt + (size_t)row * KIN + kb * 32 + gchk * 8;
      async16(gp, &Bs[buf][nr * 32]);
    }
  };

  stageB(0, 0);
  __syncthreads();

  for (int kb = 0; kb < 16; ++kb) {
    int cur = kb & 1;
    if (kb < 15) stageB(kb + 1, cur ^ 1);
    bf16x8 af[4];
#pragma unroll
    for (int i = 0; i < 4; ++i) {
      float4 f0 = *(const float4*)(pa[i] + kb * 32);
      float4 f1 = *(const float4*)(pa[i] + kb * 32 + 4);
      uint4 pk;
      pk.x = pk_bf2(f0.x, f0.y); pk.y = pk_bf2(f0.z, f0.w);
      pk.z = pk_bf2(f1.x, f1.y); pk.w = pk_bf2(f1.z, f1.w);
      af[i] = *(bf16x8*)&pk;
    }
#pragma unroll
    for (int j = 0; j < 4; ++j) {
      int nloc = wave * 64 + j * 16 + m16;
      bf16x8 b = *(const bf16x8*)(&Bs[cur][nloc * 32] + ((q ^ ((nloc >> 1) & 3)) * 8));
#pragma unroll
      for (int i = 0; i < 4; ++i)
        acc[i][j] = __builtin_amdgcn_mfma_f32_16x16x32_bf16(af[i], b, acc[i][j], 0, 0, 0);
    }
    __syncthreads();
  }

#pragma unroll
  for (int i = 0; i < 4; ++i) {
#pragma unroll
    for (int r = 0; r < 4; ++r) {
      int row = row0 + i * 16 + q * 4 + r;
      if (row < M) {
#pragma unroll
        for (int j = 0; j < 4; ++j) {
          int col = wave * 64 + j * 16 + m16;
          C[(size_t)row * F1 + col] = __float2bfloat16(acc[i][j][r]);
        }
      }
    }
  }
}

// ---------------- Aggregation, 256 features (layer 1), edge-unrolled x8 ----
// 8 nodes/block, 32 lanes/node, lane owns 8 features (16B gathers).

__global__ __launch_bounds__(256) void k_agg1(const bf16* __restrict__ H,
                                              const int* __restrict__ off,
                                              const int2* __restrict__ ew,
                                              const float* __restrict__ dinv,
                                              const float* __restrict__ bias,
                                              bf16* __restrict__ O, int N) {
  int t = threadIdx.x;
  int i = blockIdx.x * 8 + (t >> 5);
  if (i >= N) return;
  int f0 = (t & 31) * 8;
  const unsigned short* Hu = (const unsigned short*)H;
  float di = dinv[i];
  float w0 = di * di;
  float acc[8];
  {
    uint4 h = *(const uint4*)(Hu + (size_t)i * F1 + f0);
    acc[0] = w0 * bfbits(h.x & 0xffff); acc[1] = w0 * bfbits(h.x >> 16);
    acc[2] = w0 * bfbits(h.y & 0xffff); acc[3] = w0 * bfbits(h.y >> 16);
    acc[4] = w0 * bfbits(h.z & 0xffff); acc[5] = w0 * bfbits(h.z >> 16);
    acc[6] = w0 * bfbits(h.w & 0xffff); acc[7] = w0 * bfbits(h.w >> 16);
  }
  int e = off[i], e1 = off[i + 1];
  for (; e + 8 <= e1; e += 8) {
    int2 p0 = ew[e + 0], p1 = ew[e + 1], p2 = ew[e + 2], p3 = ew[e + 3];
    int2 p4 = ew[e + 4], p5 = ew[e + 5], p6 = ew[e + 6], p7 = ew[e + 7];
    uint4 g0 = *(const uint4*)(Hu + (size_t)p0.x * F1 + f0);
    uint4 g1 = *(const uint4*)(Hu + (size_t)p1.x * F1 + f0);
    uint4 g2 = *(const uint4*)(Hu + (size_t)p2.x * F1 + f0);
    uint4 g3 = *(const uint4*)(Hu + (size_t)p3.x * F1 + f0);
    uint4 g4 = *(const uint4*)(Hu + (size_t)p4.x * F1 + f0);
    uint4 g5 = *(const uint4*)(Hu + (size_t)p5.x * F1 + f0);
    uint4 g6 = *(const uint4*)(Hu + (size_t)p6.x * F1 + f0);
    uint4 g7 = *(const uint4*)(Hu + (size_t)p7.x * F1 + f0);
    accum8(acc, g0, __int_as_float(p0.y));
    accum8(acc, g1, __int_as_float(p1.y));
    accum8(acc, g2, __int_as_float(p2.y));
    accum8(acc, g3, __int_as_float(p3.y));
    accum8(acc, g4, __int_as_float(p4.y));
    accum8(acc, g5, __int_as_float(p5.y));
    accum8(acc, g6, __int_as_float(p6.y));
    accum8(acc, g7, __int_as_float(p7.y));
  }
  for (; e < e1; ++e) {
    int2 pe = ew[e];
    uint4 g = *(const uint4*)(Hu + (size_t)pe.x * F1 + f0);
    accum8(acc, g, __int_as_float(pe.y));
  }
  float4 b0 = *(const float4*)(bias + f0);
  float4 b1 = *(const float4*)(bias + f0 + 4);
  float bb[8] = {b0.x, b0.y, b0.z, b0.w, b1.x, b1.y, b1.z, b1.w};
  uint4 o;
  unsigned* op = (unsigned*)&o;
#pragma unroll
  for (int k = 0; k < 4; ++k) {
    float lo = fmaxf(acc[2 * k] + bb[2 * k], 0.f);
    float hi = fmaxf(acc[2 * k + 1] + bb[2 * k + 1], 0.f);
    op[k] = pk_bf2(lo, hi);
  }
  *(uint4*)((unsigned short*)O + (size_t)i * F1 + f0) = o;
}

// ---------------- GEMM2: h2 = out1 @ W2 (bf16 in, f32 out) ----------------

__global__ __launch_bounds__(256) void k_gemm2(const bf16* __restrict__ A,
                                               const float* __restrict__ W,
                                               float* __restrict__ C, int N) {
  __shared__ float Ws[F1 * F2];
  __shared__ float Ts[16][F1];
  int t = threadIdx.x;
  int r0 = blockIdx.x * 16;
#pragma unroll
  for (int j = 0; j < 16; ++j) Ws[t + 256 * j] = W[t + 256 * j];
  const unsigned short* Au = (const unsigned short*)A;
#pragma unroll
  for (int j = 0; j < 2; ++j) {
    int idx = t + 256 * j;
    int r = idx >> 5;
    int c8 = (idx & 31) * 8;
    int row = r0 + r;
    uint4 g = make_uint4(0, 0, 0, 0);
    if (row < N) g = *(const uint4*)(Au + (size_t)row * F1 + c8);
    float* ts = &Ts[r][c8];
    ts[0] = bfbits(g.x & 0xffff); ts[1] = bfbits(g.x >> 16);
    ts[2] = bfbits(g.y & 0xffff); ts[3] = bfbits(g.y >> 16);
    ts[4] = bfbits(g.z & 0xffff); ts[5] = bfbits(g.z >> 16);
    ts[6] = bfbits(g.w & 0xffff); ts[7] = bfbits(g.w >> 16);
  }
  __syncthreads();
  int r = t >> 4, c = t & 15;
  float acc = 0.f;
  const float4* tv = (const float4*)&Ts[r][0];
#pragma unroll 8
  for (int k4 = 0; k4 < 64; ++k4) {
    float4 a = tv[k4];
    int k = k4 * 4;
    acc = fmaf(a.x, Ws[(k + 0) * 16 + c], acc);
    acc = fmaf(a.y, Ws[(k + 1) * 16 + c], acc);
    acc = fmaf(a.z, Ws[(k + 2) * 16 + c], acc);
    acc = fmaf(a.w, Ws[(k + 3) * 16 + c], acc);
  }
  int row = r0 + r;
  if (row < N) C[(size_t)row * F2 + c] = acc;
}

// ---------------- Aggregation, 16 features (layer 2): out2=relu(agg(h2)+b2) -

__global__ __launch_bounds__(256) void k_agg16(const float* __restrict__ H,
                                               const int* __restrict__ off,
                                               const int2* __restrict__ ew,
                                               const float* __restrict__ dinv,
                                               const float* __restrict__ bias,
                                               float* __restrict__ O, int N) {
  int t = threadIdx.x;
  int i = blockIdx.x * 16 + (t >> 4);
  int f = t & 15;
  if (i >= N) return;
  float di = dinv[i];
  float acc = di * di * H[(size_t)i * F2 + f];
  int e = off[i], e1 = off[i + 1];
  for (; e + 4 <= e1; e += 4) {
    int2 p0 = ew[e + 0], p1 = ew[e + 1], p2 = ew[e + 2], p3 = ew[e + 3];
    float g0 = H[(size_t)p0.x * F2 + f];
    float g1 = H[(size_t)p1.x * F2 + f];
    float g2 = H[(size_t)p2.x * F2 + f];
    float g3 = H[(size_t)p3.x * F2 + f];
    acc = fmaf(__int_as_float(p0.y), g0, acc);
    acc = fmaf(__int_as_float(p1.y), g1, acc);
    acc = fmaf(__int_as_float(p2.y), g2, acc);
    acc = fmaf(__int_as_float(p3.y), g3, acc);
  }
  for (; e < e1; ++e) {
    int2 pe = ew[e];
    acc = fmaf(__int_as_float(pe.y), H[(size_t)pe.x * F2 + f], acc);
  }
  acc = fmaxf(acc + bias[f], 0.f);
  O[(size_t)i * F2 + f] = acc;
}

// ---------------- agg(out2) + GEMM3 + bias + log_softmax fused -------------

__global__ __launch_bounds__(256) void k_agg3_g3(const float* __restrict__ H,
                                                 const int* __restrict__ off,
                                                 const int2* __restrict__ ew,
                                                 const float* __restrict__ dinv,
                                                 const float* __restrict__ W3,
                                                 const float* __restrict__ b3,
                                                 float* __restrict__ O, int N) {
  __shared__ float W3s[F2 * F3];
  __shared__ float b3s[F3];
  __shared__ float aggs[16 * 17];
  int t = threadIdx.x;
  for (int idx = t; idx < F2 * F3; idx += 256) W3s[idx] = W3[idx];
  if (t < F3) b3s[t] = b3[t];
  __syncthreads();

  int node = t >> 4, f = t & 15;
  int i = blockIdx.x * 16 + node;
  if (i >= N) return;
  float di = dinv[i];
  float acc = di * di * H[(size_t)i * F2 + f];
  int e = off[i], e1 = off[i + 1];
  for (; e + 4 <= e1; e += 4) {
    int2 p0 = ew[e + 0], p1 = ew[e + 1], p2 = ew[e + 2], p3 = ew[e + 3];
    float g0 = H[(size_t)p0.x * F2 + f];
    float g1 = H[(size_t)p1.x * F2 + f];
    float g2 = H[(size_t)p2.x * F2 + f];
    float g3 = H[(size_t)p3.x * F2 + f];
    acc = fmaf(__int_as_float(p0.y), g0, acc);
    acc = fmaf(__int_as_float(p1.y), g1, acc);
    acc = fmaf(__int_as_float(p2.y), g2, acc);
    acc = fmaf(__int_as_float(p3.y), g3, acc);
  }
  for (; e < e1; ++e) {
    int2 pe = ew[e];
    acc = fmaf(__int_as_float(pe.y), H[(size_t)pe.x * F2 + f], acc);
  }
  aggs[node * 17 + f] = acc;

  const float* ar = &aggs[node * 17];
  float o0 = b3s[f], o1 = b3s[f + 16], o2 = (f < 8) ? b3s[f + 32] : 0.f;
#pragma unroll
  for (int k = 0; k < F2; ++k) {
    float a = ar[k];
    o0 = fmaf(a, W3s[k * F3 + f], o0);
    o1 = fmaf(a, W3s[k * F3 + f + 16], o1);
    if (f < 8) o2 = fmaf(a, W3s[k * F3 + f + 32], o2);
  }
  float m = fmaxf(o0, o1);
  if (f < 8) m = fmaxf(m, o2);
#pragma unroll
  for (int d = 1; d < 16; d <<= 1) m = fmaxf(m, __shfl_xor(m, d, 16));
  float s = __expf(o0 - m) + __expf(o1 - m) + ((f < 8) ? __expf(o2 - m) : 0.f);
#pragma unroll
  for (int d = 1; d < 16; d <<= 1) s += __shfl_xor(s, d, 16);
  float lse = m + __logf(s);
  float* orow = O + (size_t)i * F3;
  orow[f] = o0 - lse;
  orow[f + 16] = o1 - lse;
  if (f < 8) orow[f + 32] = o2 - lse;
}

// ---------------- launch ----------------

extern "C" void kernel_launch(void* const* d_in, const int* in_sizes, int n_in,
                              void* d_out, int out_size, void* d_ws, size_t ws_size,
                              hipStream_t stream) {
  const float* x  = (const float*)d_in[0];
  const int*   ei = (const int*)d_in[1];
  const float* W1 = (const float*)d_in[2];
  const float* b1 = (const float*)d_in[3];
  const float* W2 = (const float*)d_in[4];
  const float* b2 = (const float*)d_in[5];
  const float* W3 = (const float*)d_in[6];
  const float* b3 = (const float*)d_in[7];
  float* out = (float*)d_out;

  int N = in_sizes[0] / KIN;
  int E = in_sizes[1] / 2;

  char* p = (char*)d_ws;
  auto take = [&](size_t bytes) {
    char* r = p;
    p += (bytes + 255) & ~(size_t)255;
    return r;
  };
  int*   flag  = (int*)take(4);
  int*   cnt   = (int*)take((size_t)N * 4);
  int*   fill  = (int*)take((size_t)N * 4);
  int*   off   = (int*)take((size_t)(N + 1) * 4);
  float* dinv  = (float*)take((size_t)N * 4);
  int*   bsum  = (int*)take(64 * 4);
  int*   carry = (int*)take(64 * 4);
  int2*  ew    = (int2*)take((size_t)E * 8);
  unsigned short* w1t = (unsigned short*)take((size_t)KIN * F1 * 2);
  bf16*  h1    = (bf16*)take((size_t)N * F1 * 2);
  bf16*  out1  = (bf16*)take((size_t)N * F1 * 2);
  float* h2    = (float*)take((size_t)N * F2 * 4);
  float* out2  = (float*)take((size_t)N * F2 * 4);

  int nb  = (N + 255) / 256;
  int ebk = (E + 255) / 256;
  int nsc = (N + 1023) / 1024;

  k_init2<<<nb + 128, 256, 0, stream>>>(cnt, fill, ei, flag, W1, w1t, N, nb);
  k_count<<<ebk, 256, 0, stream>>>(ei, flag, cnt, E);
  k_scan1<<<nsc, 256, 0, stream>>>(cnt, off, bsum, dinv, N);
  k_scan2<<<1, 64, 0, stream>>>(bsum, carry, nsc);
  k_scan3<<<nsc, 256, 0, stream>>>(off, carry, N);
  k_scatter<<<ebk, 256, 0, stream>>>(ei, flag, off, fill, dinv, ew, E);

  k_gemm1<<<(N + 63) / 64, 256, 0, stream>>>(x, w1t, h1, N);
  k_agg1<<<(N + 7) / 8, 256, 0, stream>>>(h1, off, ew, dinv, b1, out1, N);
  k_gemm2<<<(N + 15) / 16, 256, 0, stream>>>(out1, W2, h2, N);
  k_agg16<<<(N + 15) / 16, 256, 0, stream>>>(h2, off, ew, dinv, b2, out2, N);
  k_agg3_g3<<<(N + 15) / 16, 256, 0, stream>>>(out2, off, ew, dinv, W3, b3, out, N);
}

// Round 7
// 432.240 us; speedup vs baseline: 1.1168x; 1.0108x over previous
//
#include <hip/hip_runtime.h>
#include <hip/hip_bf16.h>
#include <math.h>

typedef __hip_bfloat16 bf16;
typedef __attribute__((ext_vector_type(8))) __bf16 bf16x8;
typedef __attribute__((ext_vector_type(4))) float f32x4;

#define KIN 512
#define F1  256
#define F2  16
#define F3  40

// ---------------- helpers ----------------

__device__ inline unsigned pk_bf2(float a, float b) {
  bf16 x = __float2bfloat16(a), y = __float2bfloat16(b);
  unsigned short ux = *(unsigned short*)&x, uy = *(unsigned short*)&y;
  return (unsigned)ux | ((unsigned)uy << 16);
}
__device__ inline float bfbits(unsigned u16) {
  unsigned v = u16 << 16;
  return *(float*)&v;
}
__device__ inline void async16(const void* g, void* l) {
  __builtin_amdgcn_global_load_lds((const __attribute__((address_space(1))) void*)g,
                                   (__attribute__((address_space(3))) void*)l, 16, 0, 0);
}
__device__ inline void accum8(float* acc, uint4 h, float w) {
  acc[0] = fmaf(w, bfbits(h.x & 0xffff), acc[0]);
  acc[1] = fmaf(w, bfbits(h.x >> 16),    acc[1]);
  acc[2] = fmaf(w, bfbits(h.y & 0xffff), acc[2]);
  acc[3] = fmaf(w, bfbits(h.y >> 16),    acc[3]);
  acc[4] = fmaf(w, bfbits(h.z & 0xffff), acc[4]);
  acc[5] = fmaf(w, bfbits(h.z >> 16),    acc[5]);
  acc[6] = fmaf(w, bfbits(h.w & 0xffff), acc[6]);
  acc[7] = fmaf(w, bfbits(h.w >> 16),    acc[7]);
}

// ---------------- init: zero cnt/fill + flag + W1 transpose (fused) --------

__global__ __launch_bounds__(256) void k_init2(int* __restrict__ cnt, int* __restrict__ fill,
                                               const int* __restrict__ ei, int* __restrict__ flag,
                                               const float* __restrict__ W,
                                               unsigned short* __restrict__ Wt,
                                               int n, int nb) {
  int b = blockIdx.x;
  int t = threadIdx.x;
  if (b < nb) {
    int i = b * 256 + t;
    if (i < n) { cnt[i] = 0; fill[i] = 0; }
    if (b == 0 && t == 0)
      *flag = (ei[1] == 0 && ei[3] == 0 && ei[5] == 0 && ei[7] == 0) ? 1 : 0;
  } else {
    __shared__ float tile[32][33];
    int b2 = b - nb;
    int k0 = (b2 & 15) * 32;
    int n0 = (b2 >> 4) * 32;
    int lr = t >> 5, lc = t & 31;
#pragma unroll
    for (int rr = 0; rr < 32; rr += 8)
      tile[lr + rr][lc] = W[(size_t)(k0 + lr + rr) * F1 + n0 + lc];
    __syncthreads();
#pragma unroll
    for (int rr = 0; rr < 32; rr += 8) {
      bf16 v = __float2bfloat16(tile[lc][lr + rr]);
      Wt[(size_t)(n0 + lr + rr) * KIN + k0 + lc] = *(unsigned short*)&v;
    }
  }
}

__global__ void k_count(const int* __restrict__ ei, const int* __restrict__ flag,
                        int* __restrict__ cnt, int E) {
  int e = blockIdx.x * 256 + threadIdx.x;
  if (e >= E) return;
  int is64 = *flag;
  int d = is64 ? ei[2 * E + 2 * e] : ei[E + e];
  atomicAdd(&cnt[d], 1);
}

__global__ __launch_bounds__(256) void k_scan1(const int* __restrict__ cnt,
                                               int* __restrict__ off,
                                               int* __restrict__ bsum,
                                               float* __restrict__ dinv, int N) {
  __shared__ int s[256];
  int t = threadIdx.x;
  int base = blockIdx.x * 1024 + t * 4;
  int v0 = (base + 0 < N) ? cnt[base + 0] : 0;
  int v1 = (base + 1 < N) ? cnt[base + 1] : 0;
  int v2 = (base + 2 < N) ? cnt[base + 2] : 0;
  int v3 = (base + 3 < N) ? cnt[base + 3] : 0;
  if (base + 0 < N) dinv[base + 0] = rsqrtf((float)(v0 + 1));
  if (base + 1 < N) dinv[base + 1] = rsqrtf((float)(v1 + 1));
  if (base + 2 < N) dinv[base + 2] = rsqrtf((float)(v2 + 1));
  if (base + 3 < N) dinv[base + 3] = rsqrtf((float)(v3 + 1));
  int tsum = v0 + v1 + v2 + v3;
  s[t] = tsum;
  __syncthreads();
  for (int d = 1; d < 256; d <<= 1) {
    int u = (t >= d) ? s[t - d] : 0;
    __syncthreads();
    s[t] += u;
    __syncthreads();
  }
  int excl = s[t] - tsum;
  int p0 = excl + v0, p1 = p0 + v1, p2 = p1 + v2, p3 = p2 + v3;
  if (base + 0 < N) off[base + 1] = p0;
  if (base + 1 < N) off[base + 2] = p1;
  if (base + 2 < N) off[base + 3] = p2;
  if (base + 3 < N) off[base + 4] = p3;
  if (t == 255) bsum[blockIdx.x] = s[255];
}

__global__ void k_scan2(const int* __restrict__ bsum, int* __restrict__ carry, int nb) {
  int t = threadIdx.x;
  int v = (t < nb) ? bsum[t] : 0;
  int incl = v;
  for (int d = 1; d < 64; d <<= 1) {
    int u = __shfl_up(incl, d, 64);
    if (t >= d) incl += u;
  }
  if (t < nb) carry[t] = incl - v;
}

__global__ __launch_bounds__(256) void k_scan3(int* __restrict__ off,
                                               const int* __restrict__ carry, int N) {
  int t = threadIdx.x;
  int c = carry[blockIdx.x];
  int base = blockIdx.x * 1024 + t * 4;
#pragma unroll
  for (int k = 0; k < 4; ++k)
    if (base + k < N) off[base + k + 1] += c;
  if (blockIdx.x == 0 && t == 0) off[0] = 0;
}

__global__ void k_scatter(const int* __restrict__ ei, const int* __restrict__ flag,
                          const int* __restrict__ off, int* __restrict__ fill,
                          const float* __restrict__ dinv,
                          int2* __restrict__ ew, int E) {
  int e = blockIdx.x * 256 + threadIdx.x;
  if (e >= E) return;
  int is64 = *flag;
  int s, d;
  if (is64) { s = ei[2 * e]; d = ei[2 * E + 2 * e]; }
  else      { s = ei[e];     d = ei[E + e]; }
  int pos = off[d] + atomicAdd(&fill[d], 1);
  float w = dinv[s] * dinv[d];
  ew[pos] = make_int2(s, __float_as_int(w));
}

// ---------------- GEMM1: h1 = bf16(x) @ W1 ----------------
// 512 threads (8 waves), tile 64(M) x 256(N). Wave (wm,wn): rows [wm*32,+32),
// cols [wn*64,+64)  => 6256 waves total (6.1/SIMD TLP).
// A: register prefetch one kb ahead (raw f32), pack->bf16 at use.
// B: double-buffered LDS via global_load_lds (proven swizzle).

__global__ __launch_bounds__(512) void k_gemm1(const float* __restrict__ A,
                                               const unsigned short* __restrict__ Bt,
                                               bf16* __restrict__ C, int M) {
  __shared__ unsigned short Bs[2][256 * 32];
  int t = threadIdx.x;
  int wave = t >> 6, lane = t & 63;
  int wm = wave >> 2, wn = wave & 3;
  int row0 = blockIdx.x * 64;
  int q = lane >> 4, m16 = lane & 15;
  int brow_l = lane >> 2, bchk_p = lane & 3;

  const float* pa[2];
#pragma unroll
  for (int i = 0; i < 2; ++i) {
    int r = row0 + wm * 32 + i * 16 + m16;
    if (r >= M) r = M - 1;
    pa[i] = A + (size_t)r * KIN + q * 8;
  }

  f32x4 acc[2][4];
#pragma unroll
  for (int i = 0; i < 2; ++i)
#pragma unroll
    for (int j = 0; j < 4; ++j) acc[i][j] = {0.f, 0.f, 0.f, 0.f};

  auto stageB = [&](int kb, int buf) {
#pragma unroll
    for (int jj = 0; jj < 2; ++jj) {
      int nr = wave * 32 + jj * 16;
      int row = nr + brow_l;
      int gchk = bchk_p ^ ((row >> 1) & 3);
      const unsigned short* gp = Bt + (size_t)row * KIN + kb * 32 + gchk * 8;
      async16(gp, &Bs[buf][nr * 32]);
    }
  };

  // preload A(kb=0) raw + stage B(0)
  float4 nf0[2], nf1[2];
#pragma unroll
  for (int i = 0; i < 2; ++i) {
    nf0[i] = *(const float4*)(pa[i]);
    nf1[i] = *(const float4*)(pa[i] + 4);
  }
  stageB(0, 0);
  __syncthreads();

  for (int kb = 0; kb < 16; ++kb) {
    int cur = kb & 1;
    if (kb < 15) stageB(kb + 1, cur ^ 1);
    // pack current A from prefetched regs
    bf16x8 af[2];
#pragma unroll
    for (int i = 0; i < 2; ++i) {
      uint4 pk;
      pk.x = pk_bf2(nf0[i].x, nf0[i].y); pk.y = pk_bf2(nf0[i].z, nf0[i].w);
      pk.z = pk_bf2(nf1[i].x, nf1[i].y); pk.w = pk_bf2(nf1[i].z, nf1[i].w);
      af[i] = *(bf16x8*)&pk;
    }
    // issue next A raw loads (one kb ahead) right after consuming
    if (kb < 15) {
#pragma unroll
      for (int i = 0; i < 2; ++i) {
        nf0[i] = *(const float4*)(pa[i] + (kb + 1) * 32);
        nf1[i] = *(const float4*)(pa[i] + (kb + 1) * 32 + 4);
      }
    }
    // B from LDS + 8 MFMA
#pragma unroll
    for (int j = 0; j < 4; ++j) {
      int nloc = wn * 64 + j * 16 + m16;
      bf16x8 b = *(const bf16x8*)(&Bs[cur][nloc * 32] + ((q ^ ((nloc >> 1) & 3)) * 8));
#pragma unroll
      for (int i = 0; i < 2; ++i)
        acc[i][j] = __builtin_amdgcn_mfma_f32_16x16x32_bf16(af[i], b, acc[i][j], 0, 0, 0);
    }
    __syncthreads();
  }

  // epilogue: D[row=(lane>>4)*4+r][col=lane&15]
#pragma unroll
  for (int i = 0; i < 2; ++i) {
#pragma unroll
    for (int r = 0; r < 4; ++r) {
      int row = row0 + wm * 32 + i * 16 + q * 4 + r;
      if (row < M) {
#pragma unroll
        for (int j = 0; j < 4; ++j) {
          int col = wn * 64 + j * 16 + m16;
          C[(size_t)row * F1 + col] = __float2bfloat16(acc[i][j][r]);
        }
      }
    }
  }
}

// ---------------- Aggregation, 256 features (layer 1), edge-unrolled x8 ----

__global__ __launch_bounds__(256) void k_agg1(const bf16* __restrict__ H,
                                              const int* __restrict__ off,
                                              const int2* __restrict__ ew,
                                              const float* __restrict__ dinv,
                                              const float* __restrict__ bias,
                                              bf16* __restrict__ O, int N) {
  int t = threadIdx.x;
  int i = blockIdx.x * 8 + (t >> 5);
  if (i >= N) return;
  int f0 = (t & 31) * 8;
  const unsigned short* Hu = (const unsigned short*)H;
  float di = dinv[i];
  float w0 = di * di;
  float acc[8];
  {
    uint4 h = *(const uint4*)(Hu + (size_t)i * F1 + f0);
    acc[0] = w0 * bfbits(h.x & 0xffff); acc[1] = w0 * bfbits(h.x >> 16);
    acc[2] = w0 * bfbits(h.y & 0xffff); acc[3] = w0 * bfbits(h.y >> 16);
    acc[4] = w0 * bfbits(h.z & 0xffff); acc[5] = w0 * bfbits(h.z >> 16);
    acc[6] = w0 * bfbits(h.w & 0xffff); acc[7] = w0 * bfbits(h.w >> 16);
  }
  int e = off[i], e1 = off[i + 1];
  for (; e + 8 <= e1; e += 8) {
    int2 p0 = ew[e + 0], p1 = ew[e + 1], p2 = ew[e + 2], p3 = ew[e + 3];
    int2 p4 = ew[e + 4], p5 = ew[e + 5], p6 = ew[e + 6], p7 = ew[e + 7];
    uint4 g0 = *(const uint4*)(Hu + (size_t)p0.x * F1 + f0);
    uint4 g1 = *(const uint4*)(Hu + (size_t)p1.x * F1 + f0);
    uint4 g2 = *(const uint4*)(Hu + (size_t)p2.x * F1 + f0);
    uint4 g3 = *(const uint4*)(Hu + (size_t)p3.x * F1 + f0);
    uint4 g4 = *(const uint4*)(Hu + (size_t)p4.x * F1 + f0);
    uint4 g5 = *(const uint4*)(Hu + (size_t)p5.x * F1 + f0);
    uint4 g6 = *(const uint4*)(Hu + (size_t)p6.x * F1 + f0);
    uint4 g7 = *(const uint4*)(Hu + (size_t)p7.x * F1 + f0);
    accum8(acc, g0, __int_as_float(p0.y));
    accum8(acc, g1, __int_as_float(p1.y));
    accum8(acc, g2, __int_as_float(p2.y));
    accum8(acc, g3, __int_as_float(p3.y));
    accum8(acc, g4, __int_as_float(p4.y));
    accum8(acc, g5, __int_as_float(p5.y));
    accum8(acc, g6, __int_as_float(p6.y));
    accum8(acc, g7, __int_as_float(p7.y));
  }
  for (; e < e1; ++e) {
    int2 pe = ew[e];
    uint4 g = *(const uint4*)(Hu + (size_t)pe.x * F1 + f0);
    accum8(acc, g, __int_as_float(pe.y));
  }
  float4 b0 = *(const float4*)(bias + f0);
  float4 b1 = *(const float4*)(bias + f0 + 4);
  float bb[8] = {b0.x, b0.y, b0.z, b0.w, b1.x, b1.y, b1.z, b1.w};
  uint4 o;
  unsigned* op = (unsigned*)&o;
#pragma unroll
  for (int k = 0; k < 4; ++k) {
    float lo = fmaxf(acc[2 * k] + bb[2 * k], 0.f);
    float hi = fmaxf(acc[2 * k + 1] + bb[2 * k + 1], 0.f);
    op[k] = pk_bf2(lo, hi);
  }
  *(uint4*)((unsigned short*)O + (size_t)i * F1 + f0) = o;
}

// ---------------- GEMM2: h2 = out1 @ W2 (bf16 in, f32 out) ----------------

__global__ __launch_bounds__(256) void k_gemm2(const bf16* __restrict__ A,
                                               const float* __restrict__ W,
                                               float* __restrict__ C, int N) {
  __shared__ float Ws[F1 * F2];
  __shared__ float Ts[16][F1];
  int t = threadIdx.x;
  int r0 = blockIdx.x * 16;
#pragma unroll
  for (int j = 0; j < 16; ++j) Ws[t + 256 * j] = W[t + 256 * j];
  const unsigned short* Au = (const unsigned short*)A;
#pragma unroll
  for (int j = 0; j < 2; ++j) {
    int idx = t + 256 * j;
    int r = idx >> 5;
    int c8 = (idx & 31) * 8;
    int row = r0 + r;
    uint4 g = make_uint4(0, 0, 0, 0);
    if (row < N) g = *(const uint4*)(Au + (size_t)row * F1 + c8);
    float* ts = &Ts[r][c8];
    ts[0] = bfbits(g.x & 0xffff); ts[1] = bfbits(g.x >> 16);
    ts[2] = bfbits(g.y & 0xffff); ts[3] = bfbits(g.y >> 16);
    ts[4] = bfbits(g.z & 0xffff); ts[5] = bfbits(g.z >> 16);
    ts[6] = bfbits(g.w & 0xffff); ts[7] = bfbits(g.w >> 16);
  }
  __syncthreads();
  int r = t >> 4, c = t & 15;
  float acc = 0.f;
  const float4* tv = (const float4*)&Ts[r][0];
#pragma unroll 8
  for (int k4 = 0; k4 < 64; ++k4) {
    float4 a = tv[k4];
    int k = k4 * 4;
    acc = fmaf(a.x, Ws[(k + 0) * 16 + c], acc);
    acc = fmaf(a.y, Ws[(k + 1) * 16 + c], acc);
    acc = fmaf(a.z, Ws[(k + 2) * 16 + c], acc);
    acc = fmaf(a.w, Ws[(k + 3) * 16 + c], acc);
  }
  int row = r0 + r;
  if (row < N) C[(size_t)row * F2 + c] = acc;
}

// ---------------- Aggregation, 16 features (layer 2): out2=relu(agg(h2)+b2) -

__global__ __launch_bounds__(256) void k_agg16(const float* __restrict__ H,
                                               const int* __restrict__ off,
                                               const int2* __restrict__ ew,
                                               const float* __restrict__ dinv,
                                               const float* __restrict__ bias,
                                               float* __restrict__ O, int N) {
  int t = threadIdx.x;
  int i = blockIdx.x * 16 + (t >> 4);
  int f = t & 15;
  if (i >= N) return;
  float di = dinv[i];
  float acc = di * di * H[(size_t)i * F2 + f];
  int e = off[i], e1 = off[i + 1];
  for (; e + 4 <= e1; e += 4) {
    int2 p0 = ew[e + 0], p1 = ew[e + 1], p2 = ew[e + 2], p3 = ew[e + 3];
    float g0 = H[(size_t)p0.x * F2 + f];
    float g1 = H[(size_t)p1.x * F2 + f];
    float g2 = H[(size_t)p2.x * F2 + f];
    float g3 = H[(size_t)p3.x * F2 + f];
    acc = fmaf(__int_as_float(p0.y), g0, acc);
    acc = fmaf(__int_as_float(p1.y), g1, acc);
    acc = fmaf(__int_as_float(p2.y), g2, acc);
    acc = fmaf(__int_as_float(p3.y), g3, acc);
  }
  for (; e < e1; ++e) {
    int2 pe = ew[e];
    acc = fmaf(__int_as_float(pe.y), H[(size_t)pe.x * F2 + f], acc);
  }
  acc = fmaxf(acc + bias[f], 0.f);
  O[(size_t)i * F2 + f] = acc;
}

// ---------------- agg(out2) + GEMM3 + bias + log_softmax fused -------------

__global__ __launch_bounds__(256) void k_agg3_g3(const float* __restrict__ H,
                                                 const int* __restrict__ off,
                                                 const int2* __restrict__ ew,
                                                 const float* __restrict__ dinv,
                                                 const float* __restrict__ W3,
                                                 const float* __restrict__ b3,
                                                 float* __restrict__ O, int N) {
  __shared__ float W3s[F2 * F3];
  __shared__ float b3s[F3];
  __shared__ float aggs[16 * 17];
  int t = threadIdx.x;
  for (int idx = t; idx < F2 * F3; idx += 256) W3s[idx] = W3[idx];
  if (t < F3) b3s[t] = b3[t];
  __syncthreads();

  int node = t >> 4, f = t & 15;
  int i = blockIdx.x * 16 + node;
  if (i >= N) return;
  float di = dinv[i];
  float acc = di * di * H[(size_t)i * F2 + f];
  int e = off[i], e1 = off[i + 1];
  for (; e + 4 <= e1; e += 4) {
    int2 p0 = ew[e + 0], p1 = ew[e + 1], p2 = ew[e + 2], p3 = ew[e + 3];
    float g0 = H[(size_t)p0.x * F2 + f];
    float g1 = H[(size_t)p1.x * F2 + f];
    float g2 = H[(size_t)p2.x * F2 + f];
    float g3 = H[(size_t)p3.x * F2 + f];
    acc = fmaf(__int_as_float(p0.y), g0, acc);
    acc = fmaf(__int_as_float(p1.y), g1, acc);
    acc = fmaf(__int_as_float(p2.y), g2, acc);
    acc = fmaf(__int_as_float(p3.y), g3, acc);
  }
  for (; e < e1; ++e) {
    int2 pe = ew[e];
    acc = fmaf(__int_as_float(pe.y), H[(size_t)pe.x * F2 + f], acc);
  }
  aggs[node * 17 + f] = acc;

  const float* ar = &aggs[node * 17];
  float o0 = b3s[f], o1 = b3s[f + 16], o2 = (f < 8) ? b3s[f + 32] : 0.f;
#pragma unroll
  for (int k = 0; k < F2; ++k) {
    float a = ar[k];
    o0 = fmaf(a, W3s[k * F3 + f], o0);
    o1 = fmaf(a, W3s[k * F3 + f + 16], o1);
    if (f < 8) o2 = fmaf(a, W3s[k * F3 + f + 32], o2);
  }
  float m = fmaxf(o0, o1);
  if (f < 8) m = fmaxf(m, o2);
#pragma unroll
  for (int d = 1; d < 16; d <<= 1) m = fmaxf(m, __shfl_xor(m, d, 16));
  float s = __expf(o0 - m) + __expf(o1 - m) + ((f < 8) ? __expf(o2 - m) : 0.f);
#pragma unroll
  for (int d = 1; d < 16; d <<= 1) s += __shfl_xor(s, d, 16);
  float lse = m + __logf(s);
  float* orow = O + (size_t)i * F3;
  orow[f] = o0 - lse;
  orow[f + 16] = o1 - lse;
  if (f < 8) orow[f + 32] = o2 - lse;
}

// ---------------- launch ----------------

extern "C" void kernel_launch(void* const* d_in, const int* in_sizes, int n_in,
                              void* d_out, int out_size, void* d_ws, size_t ws_size,
                              hipStream_t stream) {
  const float* x  = (const float*)d_in[0];
  const int*   ei = (const int*)d_in[1];
  const float* W1 = (const float*)d_in[2];
  const float* b1 = (const float*)d_in[3];
  const float* W2 = (const float*)d_in[4];
  const float* b2 = (const float*)d_in[5];
  const float* W3 = (const float*)d_in[6];
  const float* b3 = (const float*)d_in[7];
  float* out = (float*)d_out;

  int N = in_sizes[0] / KIN;
  int E = in_sizes[1] / 2;

  char* p = (char*)d_ws;
  auto take = [&](size_t bytes) {
    char* r = p;
    p += (bytes + 255) & ~(size_t)255;
    return r;
  };
  int*   flag  = (int*)take(4);
  int*   cnt   = (int*)take((size_t)N * 4);
  int*   fill  = (int*)take((size_t)N * 4);
  int*   off   = (int*)take((size_t)(N + 1) * 4);
  float* dinv  = (float*)take((size_t)N * 4);
  int*   bsum  = (int*)take(64 * 4);
  int*   carry = (int*)take(64 * 4);
  int2*  ew    = (int2*)take((size_t)E * 8);
  unsigned short* w1t = (unsigned short*)take((size_t)KIN * F1 * 2);
  bf16*  h1    = (bf16*)take((size_t)N * F1 * 2);
  bf16*  out1  = (bf16*)take((size_t)N * F1 * 2);
  float* h2    = (float*)take((size_t)N * F2 * 4);
  float* out2  = (float*)take((size_t)N * F2 * 4);

  int nb  = (N + 255) / 256;
  int ebk = (E + 255) / 256;
  int nsc = (N + 1023) / 1024;

  k_init2<<<nb + 128, 256, 0, stream>>>(cnt, fill, ei, flag, W1, w1t, N, nb);
  k_count<<<ebk, 256, 0, stream>>>(ei, flag, cnt, E);
  k_scan1<<<nsc, 256, 0, stream>>>(cnt, off, bsum, dinv, N);
  k_scan2<<<1, 64, 0, stream>>>(bsum, carry, nsc);
  k_scan3<<<nsc, 256, 0, stream>>>(off, carry, N);
  k_scatter<<<ebk, 256, 0, stream>>>(ei, flag, off, fill, dinv, ew, E);

  k_gemm1<<<(N + 63) / 64, 512, 0, stream>>>(x, w1t, h1, N);
  k_agg1<<<(N + 7) / 8, 256, 0, stream>>>(h1, off, ew, dinv, b1, out1, N);
  k_gemm2<<<(N + 15) / 16, 256, 0, stream>>>(out1, W2, h2, N);
  k_agg16<<<(N + 15) / 16, 256, 0, stream>>>(h2, off, ew, dinv, b2, out2, N);
  k_agg3_g3<<<(N + 15) / 16, 256, 0, stream>>>(out2, off, ew, dinv, W3, b3, out, N);
}

// Round 8
// 401.093 us; speedup vs baseline: 1.2036x; 1.0777x over previous
//
#include <hip/hip_runtime.h>
#include <hip/hip_bf16.h>
#include <math.h>

typedef __hip_bfloat16 bf16;
typedef __attribute__((ext_vector_type(8))) __bf16 bf16x8;
typedef __attribute__((ext_vector_type(4))) float f32x4;

#define KIN 512
#define F1  256
#define F2  16
#define F3  40

// ---------------- helpers ----------------

__device__ inline unsigned pk_bf2(float a, float b) {
  bf16 x = __float2bfloat16(a), y = __float2bfloat16(b);
  unsigned short ux = *(unsigned short*)&x, uy = *(unsigned short*)&y;
  return (unsigned)ux | ((unsigned)uy << 16);
}
__device__ inline float bfbits(unsigned u16) {
  unsigned v = u16 << 16;
  return *(float*)&v;
}
__device__ inline void async16(const void* g, void* l) {
  __builtin_amdgcn_global_load_lds((const __attribute__((address_space(1))) void*)g,
                                   (__attribute__((address_space(3))) void*)l, 16, 0, 0);
}
__device__ inline void accum8(float* acc, uint4 h, float w) {
  acc[0] = fmaf(w, bfbits(h.x & 0xffff), acc[0]);
  acc[1] = fmaf(w, bfbits(h.x >> 16),    acc[1]);
  acc[2] = fmaf(w, bfbits(h.y & 0xffff), acc[2]);
  acc[3] = fmaf(w, bfbits(h.y >> 16),    acc[3]);
  acc[4] = fmaf(w, bfbits(h.z & 0xffff), acc[4]);
  acc[5] = fmaf(w, bfbits(h.z >> 16),    acc[5]);
  acc[6] = fmaf(w, bfbits(h.w & 0xffff), acc[6]);
  acc[7] = fmaf(w, bfbits(h.w >> 16),    acc[7]);
}

// ---------------- init: zero cnt/fill + flag + W1 transpose (fused) --------

__global__ __launch_bounds__(256) void k_init2(int* __restrict__ cnt, int* __restrict__ fill,
                                               const int* __restrict__ ei, int* __restrict__ flag,
                                               const float* __restrict__ W,
                                               unsigned short* __restrict__ Wt,
                                               int n, int nb) {
  int b = blockIdx.x;
  int t = threadIdx.x;
  if (b < nb) {
    int i = b * 256 + t;
    if (i < n) { cnt[i] = 0; fill[i] = 0; }
    if (b == 0 && t == 0)
      *flag = (ei[1] == 0 && ei[3] == 0 && ei[5] == 0 && ei[7] == 0) ? 1 : 0;
  } else {
    __shared__ float tile[32][33];
    int b2 = b - nb;
    int k0 = (b2 & 15) * 32;
    int n0 = (b2 >> 4) * 32;
    int lr = t >> 5, lc = t & 31;
#pragma unroll
    for (int rr = 0; rr < 32; rr += 8)
      tile[lr + rr][lc] = W[(size_t)(k0 + lr + rr) * F1 + n0 + lc];
    __syncthreads();
#pragma unroll
    for (int rr = 0; rr < 32; rr += 8) {
      bf16 v = __float2bfloat16(tile[lc][lr + rr]);
      Wt[(size_t)(n0 + lr + rr) * KIN + k0 + lc] = *(unsigned short*)&v;
    }
  }
}

// ---------------- count (atomic-bound) fused with x f32->bf16 (BW-bound) ---

__global__ __launch_bounds__(256) void k_count_conv(const int* __restrict__ ei,
                                                    const int* __restrict__ flag,
                                                    int* __restrict__ cnt, int E, int ebk,
                                                    const float* __restrict__ X,
                                                    unsigned short* __restrict__ Xb,
                                                    int total8) {
  int b = blockIdx.x;
  int t = threadIdx.x;
  if (b < ebk) {
    int e = b * 256 + t;
    if (e >= E) return;
    int is64 = *flag;
    int d = is64 ? ei[2 * E + 2 * e] : ei[E + e];
    atomicAdd(&cnt[d], 1);
  } else {
    int idx = (b - ebk) * 256 + t;      // one thread per 8 floats
    if (idx >= total8) return;
    const float4* src = (const float4*)X + (size_t)idx * 2;
    float4 f0 = src[0], f1 = src[1];
    uint4 pk;
    pk.x = pk_bf2(f0.x, f0.y); pk.y = pk_bf2(f0.z, f0.w);
    pk.z = pk_bf2(f1.x, f1.y); pk.w = pk_bf2(f1.z, f1.w);
    ((uint4*)Xb)[idx] = pk;
  }
}

__global__ __launch_bounds__(256) void k_scan1(const int* __restrict__ cnt,
                                               int* __restrict__ off,
                                               int* __restrict__ bsum,
                                               float* __restrict__ dinv, int N) {
  __shared__ int s[256];
  int t = threadIdx.x;
  int base = blockIdx.x * 1024 + t * 4;
  int v0 = (base + 0 < N) ? cnt[base + 0] : 0;
  int v1 = (base + 1 < N) ? cnt[base + 1] : 0;
  int v2 = (base + 2 < N) ? cnt[base + 2] : 0;
  int v3 = (base + 3 < N) ? cnt[base + 3] : 0;
  if (base + 0 < N) dinv[base + 0] = rsqrtf((float)(v0 + 1));
  if (base + 1 < N) dinv[base + 1] = rsqrtf((float)(v1 + 1));
  if (base + 2 < N) dinv[base + 2] = rsqrtf((float)(v2 + 1));
  if (base + 3 < N) dinv[base + 3] = rsqrtf((float)(v3 + 1));
  int tsum = v0 + v1 + v2 + v3;
  s[t] = tsum;
  __syncthreads();
  for (int d = 1; d < 256; d <<= 1) {
    int u = (t >= d) ? s[t - d] : 0;
    __syncthreads();
    s[t] += u;
    __syncthreads();
  }
  int excl = s[t] - tsum;
  int p0 = excl + v0, p1 = p0 + v1, p2 = p1 + v2, p3 = p2 + v3;
  if (base + 0 < N) off[base + 1] = p0;
  if (base + 1 < N) off[base + 2] = p1;
  if (base + 2 < N) off[base + 3] = p2;
  if (base + 3 < N) off[base + 4] = p3;
  if (t == 255) bsum[blockIdx.x] = s[255];
}

__global__ void k_scan2(const int* __restrict__ bsum, int* __restrict__ carry, int nb) {
  int t = threadIdx.x;
  int v = (t < nb) ? bsum[t] : 0;
  int incl = v;
  for (int d = 1; d < 64; d <<= 1) {
    int u = __shfl_up(incl, d, 64);
    if (t >= d) incl += u;
  }
  if (t < nb) carry[t] = incl - v;
}

__global__ __launch_bounds__(256) void k_scan3(int* __restrict__ off,
                                               const int* __restrict__ carry, int N) {
  int t = threadIdx.x;
  int c = carry[blockIdx.x];
  int base = blockIdx.x * 1024 + t * 4;
#pragma unroll
  for (int k = 0; k < 4; ++k)
    if (base + k < N) off[base + k + 1] += c;
  if (blockIdx.x == 0 && t == 0) off[0] = 0;
}

__global__ void k_scatter(const int* __restrict__ ei, const int* __restrict__ flag,
                          const int* __restrict__ off, int* __restrict__ fill,
                          const float* __restrict__ dinv,
                          int2* __restrict__ ew, int E) {
  int e = blockIdx.x * 256 + threadIdx.x;
  if (e >= E) return;
  int is64 = *flag;
  int s, d;
  if (is64) { s = ei[2 * e]; d = ei[2 * E + 2 * e]; }
  else      { s = ei[e];     d = ei[E + e]; }
  int pos = off[d] + atomicAdd(&fill[d], 1);
  float w = dinv[s] * dinv[d];
  ew[pos] = make_int2(s, __float_as_int(w));
}

// ---------------- GEMM1: h1 = xb @ W1 (bf16 x bf16), m97 structure ---------
// 128x128 tile, BK=32, 256 threads (4 waves in 2x2), both operands staged via
// global_load_lds width-16 with the proven chunk-XOR swizzle. 2-barrier K-loop.

__global__ __launch_bounds__(256) void k_gemm1(const unsigned short* __restrict__ Ab,
                                               const unsigned short* __restrict__ Bt,
                                               bf16* __restrict__ C, int M) {
  __shared__ unsigned short As[128 * 32];   // 8 KB
  __shared__ unsigned short Bs[128 * 32];   // 8 KB
  int t = threadIdx.x;
  int wave = t >> 6, lane = t & 63;
  int wm = wave >> 1, wn = wave & 1;
  int row0 = blockIdx.x * 128, col0 = blockIdx.y * 128;
  int q = lane >> 4, m16 = lane & 15;
  int srow = lane >> 2, schk = lane & 3;

  f32x4 acc[4][4];
#pragma unroll
  for (int i = 0; i < 4; ++i)
#pragma unroll
    for (int j = 0; j < 4; ++j) acc[i][j] = {0.f, 0.f, 0.f, 0.f};

  for (int kb = 0; kb < 16; ++kb) {
    __syncthreads();   // previous iteration's LDS reads complete
    // stage A: wave covers local rows [wave*32, wave*32+32): 2 issues
#pragma unroll
    for (int jj = 0; jj < 2; ++jj) {
      int lr = wave * 32 + jj * 16 + srow;
      int gr = row0 + lr; if (gr >= M) gr = M - 1;
      int gchk = schk ^ ((lr >> 1) & 3);
      async16(Ab + (size_t)gr * KIN + kb * 32 + gchk * 8,
              As + (wave * 32 + jj * 16) * 32);
    }
    // stage B: same local-row pattern over w1t columns
#pragma unroll
    for (int jj = 0; jj < 2; ++jj) {
      int lr = wave * 32 + jj * 16 + srow;
      int gchk = schk ^ ((lr >> 1) & 3);
      async16(Bt + (size_t)(col0 + lr) * KIN + kb * 32 + gchk * 8,
              Bs + (wave * 32 + jj * 16) * 32);
    }
    __syncthreads();   // staging visible
    bf16x8 af[4], bfr[4];
#pragma unroll
    for (int i = 0; i < 4; ++i) {
      int m = wm * 64 + i * 16 + m16;
      af[i] = *(const bf16x8*)(As + m * 32 + ((q ^ ((m >> 1) & 3)) * 8));
    }
#pragma unroll
    for (int j = 0; j < 4; ++j) {
      int n = wn * 64 + j * 16 + m16;
      bfr[j] = *(const bf16x8*)(Bs + n * 32 + ((q ^ ((n >> 1) & 3)) * 8));
    }
#pragma unroll
    for (int j = 0; j < 4; ++j)
#pragma unroll
      for (int i = 0; i < 4; ++i)
        acc[i][j] = __builtin_amdgcn_mfma_f32_16x16x32_bf16(af[i], bfr[j], acc[i][j], 0, 0, 0);
  }

  // epilogue: D[row=(lane>>4)*4+r][col=lane&15]
#pragma unroll
  for (int i = 0; i < 4; ++i) {
#pragma unroll
    for (int r = 0; r < 4; ++r) {
      int row = row0 + wm * 64 + i * 16 + q * 4 + r;
      if (row < M) {
#pragma unroll
        for (int j = 0; j < 4; ++j) {
          int col = col0 + wn * 64 + j * 16 + m16;
          C[(size_t)row * F1 + col] = __float2bfloat16(acc[i][j][r]);
        }
      }
    }
  }
}

// ---------------- Aggregation, 256 features (layer 1), edge-unrolled x8 ----

__global__ __launch_bounds__(256) void k_agg1(const bf16* __restrict__ H,
                                              const int* __restrict__ off,
                                              const int2* __restrict__ ew,
                                              const float* __restrict__ dinv,
                                              const float* __restrict__ bias,
                                              bf16* __restrict__ O, int N) {
  int t = threadIdx.x;
  int i = blockIdx.x * 8 + (t >> 5);
  if (i >= N) return;
  int f0 = (t & 31) * 8;
  const unsigned short* Hu = (const unsigned short*)H;
  float di = dinv[i];
  float w0 = di * di;
  float acc[8];
  {
    uint4 h = *(const uint4*)(Hu + (size_t)i * F1 + f0);
    acc[0] = w0 * bfbits(h.x & 0xffff); acc[1] = w0 * bfbits(h.x >> 16);
    acc[2] = w0 * bfbits(h.y & 0xffff); acc[3] = w0 * bfbits(h.y >> 16);
    acc[4] = w0 * bfbits(h.z & 0xffff); acc[5] = w0 * bfbits(h.z >> 16);
    acc[6] = w0 * bfbits(h.w & 0xffff); acc[7] = w0 * bfbits(h.w >> 16);
  }
  int e = off[i], e1 = off[i + 1];
  for (; e + 8 <= e1; e += 8) {
    int2 p0 = ew[e + 0], p1 = ew[e + 1], p2 = ew[e + 2], p3 = ew[e + 3];
    int2 p4 = ew[e + 4], p5 = ew[e + 5], p6 = ew[e + 6], p7 = ew[e + 7];
    uint4 g0 = *(const uint4*)(Hu + (size_t)p0.x * F1 + f0);
    uint4 g1 = *(const uint4*)(Hu + (size_t)p1.x * F1 + f0);
    uint4 g2 = *(const uint4*)(Hu + (size_t)p2.x * F1 + f0);
    uint4 g3 = *(const uint4*)(Hu + (size_t)p3.x * F1 + f0);
    uint4 g4 = *(const uint4*)(Hu + (size_t)p4.x * F1 + f0);
    uint4 g5 = *(const uint4*)(Hu + (size_t)p5.x * F1 + f0);
    uint4 g6 = *(const uint4*)(Hu + (size_t)p6.x * F1 + f0);
    uint4 g7 = *(const uint4*)(Hu + (size_t)p7.x * F1 + f0);
    accum8(acc, g0, __int_as_float(p0.y));
    accum8(acc, g1, __int_as_float(p1.y));
    accum8(acc, g2, __int_as_float(p2.y));
    accum8(acc, g3, __int_as_float(p3.y));
    accum8(acc, g4, __int_as_float(p4.y));
    accum8(acc, g5, __int_as_float(p5.y));
    accum8(acc, g6, __int_as_float(p6.y));
    accum8(acc, g7, __int_as_float(p7.y));
  }
  for (; e < e1; ++e) {
    int2 pe = ew[e];
    uint4 g = *(const uint4*)(Hu + (size_t)pe.x * F1 + f0);
    accum8(acc, g, __int_as_float(pe.y));
  }
  float4 b0 = *(const float4*)(bias + f0);
  float4 b1 = *(const float4*)(bias + f0 + 4);
  float bb[8] = {b0.x, b0.y, b0.z, b0.w, b1.x, b1.y, b1.z, b1.w};
  uint4 o;
  unsigned* op = (unsigned*)&o;
#pragma unroll
  for (int k = 0; k < 4; ++k) {
    float lo = fmaxf(acc[2 * k] + bb[2 * k], 0.f);
    float hi = fmaxf(acc[2 * k + 1] + bb[2 * k + 1], 0.f);
    op[k] = pk_bf2(lo, hi);
  }
  *(uint4*)((unsigned short*)O + (size_t)i * F1 + f0) = o;
}

// ---------------- GEMM2: h2 = out1 @ W2 (bf16 in, f32 out) ----------------

__global__ __launch_bounds__(256) void k_gemm2(const bf16* __restrict__ A,
                                               const float* __restrict__ W,
                                               float* __restrict__ C, int N) {
  __shared__ float Ws[F1 * F2];
  __shared__ float Ts[16][F1];
  int t = threadIdx.x;
  int r0 = blockIdx.x * 16;
#pragma unroll
  for (int j = 0; j < 16; ++j) Ws[t + 256 * j] = W[t + 256 * j];
  const unsigned short* Au = (const unsigned short*)A;
#pragma unroll
  for (int j = 0; j < 2; ++j) {
    int idx = t + 256 * j;
    int r = idx >> 5;
    int c8 = (idx & 31) * 8;
    int row = r0 + r;
    uint4 g = make_uint4(0, 0, 0, 0);
    if (row < N) g = *(const uint4*)(Au + (size_t)row * F1 + c8);
    float* ts = &Ts[r][c8];
    ts[0] = bfbits(g.x & 0xffff); ts[1] = bfbits(g.x >> 16);
    ts[2] = bfbits(g.y & 0xffff); ts[3] = bfbits(g.y >> 16);
    ts[4] = bfbits(g.z & 0xffff); ts[5] = bfbits(g.z >> 16);
    ts[6] = bfbits(g.w & 0xffff); ts[7] = bfbits(g.w >> 16);
  }
  __syncthreads();
  int r = t >> 4, c = t & 15;
  float acc = 0.f;
  const float4* tv = (const float4*)&Ts[r][0];
#pragma unroll 8
  for (int k4 = 0; k4 < 64; ++k4) {
    float4 a = tv[k4];
    int k = k4 * 4;
    acc = fmaf(a.x, Ws[(k + 0) * 16 + c], acc);
    acc = fmaf(a.y, Ws[(k + 1) * 16 + c], acc);
    acc = fmaf(a.z, Ws[(k + 2) * 16 + c], acc);
    acc = fmaf(a.w, Ws[(k + 3) * 16 + c], acc);
  }
  int row = r0 + r;
  if (row < N) C[(size_t)row * F2 + c] = acc;
}

// ---------------- Aggregation, 16 features (layer 2) ----------------

__global__ __launch_bounds__(256) void k_agg16(const float* __restrict__ H,
                                               const int* __restrict__ off,
                                               const int2* __restrict__ ew,
                                               const float* __restrict__ dinv,
                                               const float* __restrict__ bias,
                                               float* __restrict__ O, int N) {
  int t = threadIdx.x;
  int i = blockIdx.x * 16 + (t >> 4);
  int f = t & 15;
  if (i >= N) return;
  float di = dinv[i];
  float acc = di * di * H[(size_t)i * F2 + f];
  int e = off[i], e1 = off[i + 1];
  for (; e + 4 <= e1; e += 4) {
    int2 p0 = ew[e + 0], p1 = ew[e + 1], p2 = ew[e + 2], p3 = ew[e + 3];
    float g0 = H[(size_t)p0.x * F2 + f];
    float g1 = H[(size_t)p1.x * F2 + f];
    float g2 = H[(size_t)p2.x * F2 + f];
    float g3 = H[(size_t)p3.x * F2 + f];
    acc = fmaf(__int_as_float(p0.y), g0, acc);
    acc = fmaf(__int_as_float(p1.y), g1, acc);
    acc = fmaf(__int_as_float(p2.y), g2, acc);
    acc = fmaf(__int_as_float(p3.y), g3, acc);
  }
  for (; e < e1; ++e) {
    int2 pe = ew[e];
    acc = fmaf(__int_as_float(pe.y), H[(size_t)pe.x * F2 + f], acc);
  }
  acc = fmaxf(acc + bias[f], 0.f);
  O[(size_t)i * F2 + f] = acc;
}

// ---------------- agg(out2) + GEMM3 + bias + log_softmax fused -------------

__global__ __launch_bounds__(256) void k_agg3_g3(const float* __restrict__ H,
                                                 const int* __restrict__ off,
                                                 const int2* __restrict__ ew,
                                                 const float* __restrict__ dinv,
                                                 const float* __restrict__ W3,
                                                 const float* __restrict__ b3,
                                                 float* __restrict__ O, int N) {
  __shared__ float W3s[F2 * F3];
  __shared__ float b3s[F3];
  __shared__ float aggs[16 * 17];
  int t = threadIdx.x;
  for (int idx = t; idx < F2 * F3; idx += 256) W3s[idx] = W3[idx];
  if (t < F3) b3s[t] = b3[t];
  __syncthreads();

  int node = t >> 4, f = t & 15;
  int i = blockIdx.x * 16 + node;
  if (i >= N) return;
  float di = dinv[i];
  float acc = di * di * H[(size_t)i * F2 + f];
  int e = off[i], e1 = off[i + 1];
  for (; e + 4 <= e1; e += 4) {
    int2 p0 = ew[e + 0], p1 = ew[e + 1], p2 = ew[e + 2], p3 = ew[e + 3];
    float g0 = H[(size_t)p0.x * F2 + f];
    float g1 = H[(size_t)p1.x * F2 + f];
    float g2 = H[(size_t)p2.x * F2 + f];
    float g3 = H[(size_t)p3.x * F2 + f];
    acc = fmaf(__int_as_float(p0.y), g0, acc);
    acc = fmaf(__int_as_float(p1.y), g1, acc);
    acc = fmaf(__int_as_float(p2.y), g2, acc);
    acc = fmaf(__int_as_float(p3.y), g3, acc);
  }
  for (; e < e1; ++e) {
    int2 pe = ew[e];
    acc = fmaf(__int_as_float(pe.y), H[(size_t)pe.x * F2 + f], acc);
  }
  aggs[node * 17 + f] = acc;

  const float* ar = &aggs[node * 17];
  float o0 = b3s[f], o1 = b3s[f + 16], o2 = (f < 8) ? b3s[f + 32] : 0.f;
#pragma unroll
  for (int k = 0; k < F2; ++k) {
    float a = ar[k];
    o0 = fmaf(a, W3s[k * F3 + f], o0);
    o1 = fmaf(a, W3s[k * F3 + f + 16], o1);
    if (f < 8) o2 = fmaf(a, W3s[k * F3 + f + 32], o2);
  }
  float m = fmaxf(o0, o1);
  if (f < 8) m = fmaxf(m, o2);
#pragma unroll
  for (int d = 1; d < 16; d <<= 1) m = fmaxf(m, __shfl_xor(m, d, 16));
  float s = __expf(o0 - m) + __expf(o1 - m) + ((f < 8) ? __expf(o2 - m) : 0.f);
#pragma unroll
  for (int d = 1; d < 16; d <<= 1) s += __shfl_xor(s, d, 16);
  float lse = m + __logf(s);
  float* orow = O + (size_t)i * F3;
  orow[f] = o0 - lse;
  orow[f + 16] = o1 - lse;
  if (f < 8) orow[f + 32] = o2 - lse;
}

// ---------------- launch ----------------

extern "C" void kernel_launch(void* const* d_in, const int* in_sizes, int n_in,
                              void* d_out, int out_size, void* d_ws, size_t ws_size,
                              hipStream_t stream) {
  const float* x  = (const float*)d_in[0];
  const int*   ei = (const int*)d_in[1];
  const float* W1 = (const float*)d_in[2];
  const float* b1 = (const float*)d_in[3];
  const float* W2 = (const float*)d_in[4];
  const float* b2 = (const float*)d_in[5];
  const float* W3 = (const float*)d_in[6];
  const float* b3 = (const float*)d_in[7];
  float* out = (float*)d_out;

  int N = in_sizes[0] / KIN;
  int E = in_sizes[1] / 2;

  char* p = (char*)d_ws;
  auto take = [&](size_t bytes) {
    char* r = p;
    p += (bytes + 255) & ~(size_t)255;
    return r;
  };
  int*   flag  = (int*)take(4);
  int*   cnt   = (int*)take((size_t)N * 4);
  int*   fill  = (int*)take((size_t)N * 4);
  int*   off   = (int*)take((size_t)(N + 1) * 4);
  float* dinv  = (float*)take((size_t)N * 4);
  int*   bsum  = (int*)take(64 * 4);
  int*   carry = (int*)take(64 * 4);
  int2*  ew    = (int2*)take((size_t)E * 8);
  unsigned short* w1t = (unsigned short*)take((size_t)KIN * F1 * 2);
  unsigned short* xb  = (unsigned short*)take((size_t)N * KIN * 2);
  bf16*  h1    = (bf16*)take((size_t)N * F1 * 2);
  bf16*  out1  = (bf16*)take((size_t)N * F1 * 2);
  float* h2    = (float*)take((size_t)N * F2 * 4);
  float* out2  = (float*)take((size_t)N * F2 * 4);

  int nb  = (N + 255) / 256;
  int ebk = (E + 255) / 256;
  int nsc = (N + 1023) / 1024;
  int total8 = (N * KIN) / 8;                 // threads for x conversion
  int cvb = (total8 + 255) / 256;

  k_init2<<<nb + 128, 256, 0, stream>>>(cnt, fill, ei, flag, W1, w1t, N, nb);
  k_count_conv<<<ebk + cvb, 256, 0, stream>>>(ei, flag, cnt, E, ebk, x, xb, total8);
  k_scan1<<<nsc, 256, 0, stream>>>(cnt, off, bsum, dinv, N);
  k_scan2<<<1, 64, 0, stream>>>(bsum, carry, nsc);
  k_scan3<<<nsc, 256, 0, stream>>>(off, carry, N);
  k_scatter<<<ebk, 256, 0, stream>>>(ei, flag, off, fill, dinv, ew, E);

  dim3 g1((N + 127) / 128, F1 / 128);
  k_gemm1<<<g1, 256, 0, stream>>>(xb, w1t, h1, N);
  k_agg1<<<(N + 7) / 8, 256, 0, stream>>>(h1, off, ew, dinv, b1, out1, N);
  k_gemm2<<<(N + 15) / 16, 256, 0, stream>>>(out1, W2, h2, N);
  k_agg16<<<(N + 15) / 16, 256, 0, stream>>>(h2, off, ew, dinv, b2, out2, N);
  k_agg3_g3<<<(N + 15) / 16, 256, 0, stream>>>(out2, off, ew, dinv, W3, b3, out, N);
}

// Round 9
// 357.349 us; speedup vs baseline: 1.3509x; 1.1224x over previous
//
#include <hip/hip_runtime.h>
#include <hip/hip_bf16.h>
#include <math.h>

typedef __hip_bfloat16 bf16;
typedef __attribute__((ext_vector_type(8))) __bf16 bf16x8;
typedef __attribute__((ext_vector_type(4))) float f32x4;

#define KIN 512
#define F1  256
#define F2  16
#define F3  40

// ---------------- helpers ----------------

__device__ inline unsigned pk_bf2(float a, float b) {
  bf16 x = __float2bfloat16(a), y = __float2bfloat16(b);
  unsigned short ux = *(unsigned short*)&x, uy = *(unsigned short*)&y;
  return (unsigned)ux | ((unsigned)uy << 16);
}
__device__ inline float bfbits(unsigned u16) {
  unsigned v = u16 << 16;
  return *(float*)&v;
}
__device__ inline void async16(const void* g, void* l) {
  __builtin_amdgcn_global_load_lds((const __attribute__((address_space(1))) void*)g,
                                   (__attribute__((address_space(3))) void*)l, 16, 0, 0);
}
__device__ inline void accum8(float* acc, uint4 h, float w) {
  acc[0] = fmaf(w, bfbits(h.x & 0xffff), acc[0]);
  acc[1] = fmaf(w, bfbits(h.x >> 16),    acc[1]);
  acc[2] = fmaf(w, bfbits(h.y & 0xffff), acc[2]);
  acc[3] = fmaf(w, bfbits(h.y >> 16),    acc[3]);
  acc[4] = fmaf(w, bfbits(h.z & 0xffff), acc[4]);
  acc[5] = fmaf(w, bfbits(h.z >> 16),    acc[5]);
  acc[6] = fmaf(w, bfbits(h.w & 0xffff), acc[6]);
  acc[7] = fmaf(w, bfbits(h.w >> 16),    acc[7]);
}

// ---------------- init: zero cnt + flag + W1 transpose (fused) -------------

__global__ __launch_bounds__(256) void k_init2(int* __restrict__ cnt,
                                               const int* __restrict__ ei, int* __restrict__ flag,
                                               const float* __restrict__ W,
                                               unsigned short* __restrict__ Wt,
                                               int n, int nb) {
  int b = blockIdx.x;
  int t = threadIdx.x;
  if (b < nb) {
    int i = b * 256 + t;
    if (i < n) cnt[i] = 0;
    if (b == 0 && t == 0)
      *flag = (ei[1] == 0 && ei[3] == 0 && ei[5] == 0 && ei[7] == 0) ? 1 : 0;
  } else {
    __shared__ float tile[32][33];
    int b2 = b - nb;
    int k0 = (b2 & 15) * 32;
    int n0 = (b2 >> 4) * 32;
    int lr = t >> 5, lc = t & 31;
#pragma unroll
    for (int rr = 0; rr < 32; rr += 8)
      tile[lr + rr][lc] = W[(size_t)(k0 + lr + rr) * F1 + n0 + lc];
    __syncthreads();
#pragma unroll
    for (int rr = 0; rr < 32; rr += 8) {
      bf16 v = __float2bfloat16(tile[lc][lr + rr]);
      Wt[(size_t)(n0 + lr + rr) * KIN + k0 + lc] = *(unsigned short*)&v;
    }
  }
}

// ---- count (atomic, returns rank) interleaved with x f32->bf16 streaming ---
// Block roles interleaved (1 count : ~4 conv) so atomic-latency waves and
// BW-streaming waves co-reside on each CU (dispatch is in blockIdx order).

__global__ __launch_bounds__(256) void k_count_conv(const int* __restrict__ ei,
                                                    const int* __restrict__ flag,
                                                    int* __restrict__ cnt,
                                                    int* __restrict__ rank,
                                                    int E, int nct, int stride,
                                                    const float* __restrict__ X,
                                                    unsigned short* __restrict__ Xb,
                                                    int total8) {
  int b = blockIdx.x;
  int t = threadIdx.x;
  bool is_cnt = (b % stride == 0) && (b / stride < nct);
  if (is_cnt) {
    int e = (b / stride) * 256 + t;
    if (e >= E) return;
    int is64 = *flag;
    int d = is64 ? ei[2 * E + 2 * e] : ei[E + e];
    rank[e] = atomicAdd(&cnt[d], 1);
  } else {
    int nb_before = (b + stride - 1) / stride;
    if (nb_before > nct) nb_before = nct;
    int idx = (b - nb_before) * 256 + t;
    if (idx >= total8) return;
    const float4* src = (const float4*)X + (size_t)idx * 2;
    float4 f0 = src[0], f1 = src[1];
    uint4 pk;
    pk.x = pk_bf2(f0.x, f0.y); pk.y = pk_bf2(f0.z, f0.w);
    pk.z = pk_bf2(f1.x, f1.y); pk.w = pk_bf2(f1.z, f1.w);
    ((uint4*)Xb)[idx] = pk;
  }
}

__global__ __launch_bounds__(256) void k_scan1(const int* __restrict__ cnt,
                                               int* __restrict__ off,
                                               int* __restrict__ bsum,
                                               float* __restrict__ dinv, int N) {
  __shared__ int s[256];
  int t = threadIdx.x;
  int base = blockIdx.x * 1024 + t * 4;
  int v0 = (base + 0 < N) ? cnt[base + 0] : 0;
  int v1 = (base + 1 < N) ? cnt[base + 1] : 0;
  int v2 = (base + 2 < N) ? cnt[base + 2] : 0;
  int v3 = (base + 3 < N) ? cnt[base + 3] : 0;
  if (base + 0 < N) dinv[base + 0] = rsqrtf((float)(v0 + 1));
  if (base + 1 < N) dinv[base + 1] = rsqrtf((float)(v1 + 1));
  if (base + 2 < N) dinv[base + 2] = rsqrtf((float)(v2 + 1));
  if (base + 3 < N) dinv[base + 3] = rsqrtf((float)(v3 + 1));
  int tsum = v0 + v1 + v2 + v3;
  s[t] = tsum;
  __syncthreads();
  for (int d = 1; d < 256; d <<= 1) {
    int u = (t >= d) ? s[t - d] : 0;
    __syncthreads();
    s[t] += u;
    __syncthreads();
  }
  int excl = s[t] - tsum;
  int p0 = excl + v0, p1 = p0 + v1, p2 = p1 + v2, p3 = p2 + v3;
  if (base + 0 < N) off[base + 1] = p0;
  if (base + 1 < N) off[base + 2] = p1;
  if (base + 2 < N) off[base + 3] = p2;
  if (base + 3 < N) off[base + 4] = p3;
  if (t == 255) bsum[blockIdx.x] = s[255];
}

__global__ void k_scan2(const int* __restrict__ bsum, int* __restrict__ carry, int nb) {
  int t = threadIdx.x;
  int v = (t < nb) ? bsum[t] : 0;
  int incl = v;
  for (int d = 1; d < 64; d <<= 1) {
    int u = __shfl_up(incl, d, 64);
    if (t >= d) incl += u;
  }
  if (t < nb) carry[t] = incl - v;
}

__global__ __launch_bounds__(256) void k_scan3(int* __restrict__ off,
                                               const int* __restrict__ carry, int N) {
  int t = threadIdx.x;
  int c = carry[blockIdx.x];
  int base = blockIdx.x * 1024 + t * 4;
#pragma unroll
  for (int k = 0; k < 4; ++k)
    if (base + k < N) off[base + k + 1] += c;
  if (blockIdx.x == 0 && t == 0) off[0] = 0;
}

// atomic-free scatter: pos = off[d] + rank[e]
__global__ void k_scatter(const int* __restrict__ ei, const int* __restrict__ flag,
                          const int* __restrict__ off, const int* __restrict__ rank,
                          const float* __restrict__ dinv,
                          int2* __restrict__ ew, int E) {
  int e = blockIdx.x * 256 + threadIdx.x;
  if (e >= E) return;
  int is64 = *flag;
  int s, d;
  if (is64) { s = ei[2 * e]; d = ei[2 * E + 2 * e]; }
  else      { s = ei[e];     d = ei[E + e]; }
  int pos = off[d] + rank[e];
  float w = dinv[s] * dinv[d];
  ew[pos] = make_int2(s, __float_as_int(w));
}

// ---------------- GEMM1: h1 = xb @ W1 (bf16 x bf16), m97 structure ---------

__global__ __launch_bounds__(256) void k_gemm1(const unsigned short* __restrict__ Ab,
                                               const unsigned short* __restrict__ Bt,
                                               bf16* __restrict__ C, int M) {
  __shared__ unsigned short As[128 * 32];
  __shared__ unsigned short Bs[128 * 32];
  int t = threadIdx.x;
  int wave = t >> 6, lane = t & 63;
  int wm = wave >> 1, wn = wave & 1;
  int row0 = blockIdx.x * 128, col0 = blockIdx.y * 128;
  int q = lane >> 4, m16 = lane & 15;
  int srow = lane >> 2, schk = lane & 3;

  f32x4 acc[4][4];
#pragma unroll
  for (int i = 0; i < 4; ++i)
#pragma unroll
    for (int j = 0; j < 4; ++j) acc[i][j] = {0.f, 0.f, 0.f, 0.f};

  for (int kb = 0; kb < 16; ++kb) {
    __syncthreads();
#pragma unroll
    for (int jj = 0; jj < 2; ++jj) {
      int lr = wave * 32 + jj * 16 + srow;
      int gr = row0 + lr; if (gr >= M) gr = M - 1;
      int gchk = schk ^ ((lr >> 1) & 3);
      async16(Ab + (size_t)gr * KIN + kb * 32 + gchk * 8,
              As + (wave * 32 + jj * 16) * 32);
    }
#pragma unroll
    for (int jj = 0; jj < 2; ++jj) {
      int lr = wave * 32 + jj * 16 + srow;
      int gchk = schk ^ ((lr >> 1) & 3);
      async16(Bt + (size_t)(col0 + lr) * KIN + kb * 32 + gchk * 8,
              Bs + (wave * 32 + jj * 16) * 32);
    }
    __syncthreads();
    bf16x8 af[4], bfr[4];
#pragma unroll
    for (int i = 0; i < 4; ++i) {
      int m = wm * 64 + i * 16 + m16;
      af[i] = *(const bf16x8*)(As + m * 32 + ((q ^ ((m >> 1) & 3)) * 8));
    }
#pragma unroll
    for (int j = 0; j < 4; ++j) {
      int n = wn * 64 + j * 16 + m16;
      bfr[j] = *(const bf16x8*)(Bs + n * 32 + ((q ^ ((n >> 1) & 3)) * 8));
    }
#pragma unroll
    for (int j = 0; j < 4; ++j)
#pragma unroll
      for (int i = 0; i < 4; ++i)
        acc[i][j] = __builtin_amdgcn_mfma_f32_16x16x32_bf16(af[i], bfr[j], acc[i][j], 0, 0, 0);
  }

#pragma unroll
  for (int i = 0; i < 4; ++i) {
#pragma unroll
    for (int r = 0; r < 4; ++r) {
      int row = row0 + wm * 64 + i * 16 + q * 4 + r;
      if (row < M) {
#pragma unroll
        for (int j = 0; j < 4; ++j) {
          int col = col0 + wn * 64 + j * 16 + m16;
          C[(size_t)row * F1 + col] = __float2bfloat16(acc[i][j][r]);
        }
      }
    }
  }
}

// ---------------- Aggregation, 256 features (layer 1), edge-unrolled x8 ----

__global__ __launch_bounds__(256) void k_agg1(const bf16* __restrict__ H,
                                              const int* __restrict__ off,
                                              const int2* __restrict__ ew,
                                              const float* __restrict__ dinv,
                                              const float* __restrict__ bias,
                                              bf16* __restrict__ O, int N) {
  int t = threadIdx.x;
  int i = blockIdx.x * 8 + (t >> 5);
  if (i >= N) return;
  int f0 = (t & 31) * 8;
  const unsigned short* Hu = (const unsigned short*)H;
  float di = dinv[i];
  float w0 = di * di;
  float acc[8];
  {
    uint4 h = *(const uint4*)(Hu + (size_t)i * F1 + f0);
    acc[0] = w0 * bfbits(h.x & 0xffff); acc[1] = w0 * bfbits(h.x >> 16);
    acc[2] = w0 * bfbits(h.y & 0xffff); acc[3] = w0 * bfbits(h.y >> 16);
    acc[4] = w0 * bfbits(h.z & 0xffff); acc[5] = w0 * bfbits(h.z >> 16);
    acc[6] = w0 * bfbits(h.w & 0xffff); acc[7] = w0 * bfbits(h.w >> 16);
  }
  int e = off[i], e1 = off[i + 1];
  for (; e + 8 <= e1; e += 8) {
    int2 p0 = ew[e + 0], p1 = ew[e + 1], p2 = ew[e + 2], p3 = ew[e + 3];
    int2 p4 = ew[e + 4], p5 = ew[e + 5], p6 = ew[e + 6], p7 = ew[e + 7];
    uint4 g0 = *(const uint4*)(Hu + (size_t)p0.x * F1 + f0);
    uint4 g1 = *(const uint4*)(Hu + (size_t)p1.x * F1 + f0);
    uint4 g2 = *(const uint4*)(Hu + (size_t)p2.x * F1 + f0);
    uint4 g3 = *(const uint4*)(Hu + (size_t)p3.x * F1 + f0);
    uint4 g4 = *(const uint4*)(Hu + (size_t)p4.x * F1 + f0);
    uint4 g5 = *(const uint4*)(Hu + (size_t)p5.x * F1 + f0);
    uint4 g6 = *(const uint4*)(Hu + (size_t)p6.x * F1 + f0);
    uint4 g7 = *(const uint4*)(Hu + (size_t)p7.x * F1 + f0);
    accum8(acc, g0, __int_as_float(p0.y));
    accum8(acc, g1, __int_as_float(p1.y));
    accum8(acc, g2, __int_as_float(p2.y));
    accum8(acc, g3, __int_as_float(p3.y));
    accum8(acc, g4, __int_as_float(p4.y));
    accum8(acc, g5, __int_as_float(p5.y));
    accum8(acc, g6, __int_as_float(p6.y));
    accum8(acc, g7, __int_as_float(p7.y));
  }
  for (; e < e1; ++e) {
    int2 pe = ew[e];
    uint4 g = *(const uint4*)(Hu + (size_t)pe.x * F1 + f0);
    accum8(acc, g, __int_as_float(pe.y));
  }
  float4 b0 = *(const float4*)(bias + f0);
  float4 b1 = *(const float4*)(bias + f0 + 4);
  float bb[8] = {b0.x, b0.y, b0.z, b0.w, b1.x, b1.y, b1.z, b1.w};
  uint4 o;
  unsigned* op = (unsigned*)&o;
#pragma unroll
  for (int k = 0; k < 4; ++k) {
    float lo = fmaxf(acc[2 * k] + bb[2 * k], 0.f);
    float hi = fmaxf(acc[2 * k + 1] + bb[2 * k + 1], 0.f);
    op[k] = pk_bf2(lo, hi);
  }
  *(uint4*)((unsigned short*)O + (size_t)i * F1 + f0) = o;
}

// ---------------- GEMM2: h2 = out1 @ W2 (bf16 in, f32 out) ----------------

__global__ __launch_bounds__(256) void k_gemm2(const bf16* __restrict__ A,
                                               const float* __restrict__ W,
                                               float* __restrict__ C, int N) {
  __shared__ float Ws[F1 * F2];
  __shared__ float Ts[16][F1];
  int t = threadIdx.x;
  int r0 = blockIdx.x * 16;
#pragma unroll
  for (int j = 0; j < 16; ++j) Ws[t + 256 * j] = W[t + 256 * j];
  const unsigned short* Au = (const unsigned short*)A;
#pragma unroll
  for (int j = 0; j < 2; ++j) {
    int idx = t + 256 * j;
    int r = idx >> 5;
    int c8 = (idx & 31) * 8;
    int row = r0 + r;
    uint4 g = make_uint4(0, 0, 0, 0);
    if (row < N) g = *(const uint4*)(Au + (size_t)row * F1 + c8);
    float* ts = &Ts[r][c8];
    ts[0] = bfbits(g.x & 0xffff); ts[1] = bfbits(g.x >> 16);
    ts[2] = bfbits(g.y & 0xffff); ts[3] = bfbits(g.y >> 16);
    ts[4] = bfbits(g.z & 0xffff); ts[5] = bfbits(g.z >> 16);
    ts[6] = bfbits(g.w & 0xffff); ts[7] = bfbits(g.w >> 16);
  }
  __syncthreads();
  int r = t >> 4, c = t & 15;
  float acc = 0.f;
  const float4* tv = (const float4*)&Ts[r][0];
#pragma unroll 8
  for (int k4 = 0; k4 < 64; ++k4) {
    float4 a = tv[k4];
    int k = k4 * 4;
    acc = fmaf(a.x, Ws[(k + 0) * 16 + c], acc);
    acc = fmaf(a.y, Ws[(k + 1) * 16 + c], acc);
    acc = fmaf(a.z, Ws[(k + 2) * 16 + c], acc);
    acc = fmaf(a.w, Ws[(k + 3) * 16 + c], acc);
  }
  int row = r0 + r;
  if (row < N) C[(size_t)row * F2 + c] = acc;
}

// ---------------- Aggregation, 16 features (layer 2) ----------------

__global__ __launch_bounds__(256) void k_agg16(const float* __restrict__ H,
                                               const int* __restrict__ off,
                                               const int2* __restrict__ ew,
                                               const float* __restrict__ dinv,
                                               const float* __restrict__ bias,
                                               float* __restrict__ O, int N) {
  int t = threadIdx.x;
  int i = blockIdx.x * 16 + (t >> 4);
  int f = t & 15;
  if (i >= N) return;
  float di = dinv[i];
  float acc = di * di * H[(size_t)i * F2 + f];
  int e = off[i], e1 = off[i + 1];
  for (; e + 4 <= e1; e += 4) {
    int2 p0 = ew[e + 0], p1 = ew[e + 1], p2 = ew[e + 2], p3 = ew[e + 3];
    float g0 = H[(size_t)p0.x * F2 + f];
    float g1 = H[(size_t)p1.x * F2 + f];
    float g2 = H[(size_t)p2.x * F2 + f];
    float g3 = H[(size_t)p3.x * F2 + f];
    acc = fmaf(__int_as_float(p0.y), g0, acc);
    acc = fmaf(__int_as_float(p1.y), g1, acc);
    acc = fmaf(__int_as_float(p2.y), g2, acc);
    acc = fmaf(__int_as_float(p3.y), g3, acc);
  }
  for (; e < e1; ++e) {
    int2 pe = ew[e];
    acc = fmaf(__int_as_float(pe.y), H[(size_t)pe.x * F2 + f], acc);
  }
  acc = fmaxf(acc + bias[f], 0.f);
  O[(size_t)i * F2 + f] = acc;
}

// ---------------- agg(out2) + GEMM3 + bias + log_softmax fused -------------

__global__ __launch_bounds__(256) void k_agg3_g3(const float* __restrict__ H,
                                                 const int* __restrict__ off,
                                                 const int2* __restrict__ ew,
                                                 const float* __restrict__ dinv,
                                                 const float* __restrict__ W3,
                                                 const float* __restrict__ b3,
                                                 float* __restrict__ O, int N) {
  __shared__ float W3s[F2 * F3];
  __shared__ float b3s[F3];
  __shared__ float aggs[16 * 17];
  int t = threadIdx.x;
  for (int idx = t; idx < F2 * F3; idx += 256) W3s[idx] = W3[idx];
  if (t < F3) b3s[t] = b3[t];
  __syncthreads();

  int node = t >> 4, f = t & 15;
  int i = blockIdx.x * 16 + node;
  if (i >= N) return;
  float di = dinv[i];
  float acc = di * di * H[(size_t)i * F2 + f];
  int e = off[i], e1 = off[i + 1];
  for (; e + 4 <= e1; e += 4) {
    int2 p0 = ew[e + 0], p1 = ew[e + 1], p2 = ew[e + 2], p3 = ew[e + 3];
    float g0 = H[(size_t)p0.x * F2 + f];
    float g1 = H[(size_t)p1.x * F2 + f];
    float g2 = H[(size_t)p2.x * F2 + f];
    float g3 = H[(size_t)p3.x * F2 + f];
    acc = fmaf(__int_as_float(p0.y), g0, acc);
    acc = fmaf(__int_as_float(p1.y), g1, acc);
    acc = fmaf(__int_as_float(p2.y), g2, acc);
    acc = fmaf(__int_as_float(p3.y), g3, acc);
  }
  for (; e < e1; ++e) {
    int2 pe = ew[e];
    acc = fmaf(__int_as_float(pe.y), H[(size_t)pe.x * F2 + f], acc);
  }
  aggs[node * 17 + f] = acc;

  const float* ar = &aggs[node * 17];
  float o0 = b3s[f], o1 = b3s[f + 16], o2 = (f < 8) ? b3s[f + 32] : 0.f;
#pragma unroll
  for (int k = 0; k < F2; ++k) {
    float a = ar[k];
    o0 = fmaf(a, W3s[k * F3 + f], o0);
    o1 = fmaf(a, W3s[k * F3 + f + 16], o1);
    if (f < 8) o2 = fmaf(a, W3s[k * F3 + f + 32], o2);
  }
  float m = fmaxf(o0, o1);
  if (f < 8) m = fmaxf(m, o2);
#pragma unroll
  for (int d = 1; d < 16; d <<= 1) m = fmaxf(m, __shfl_xor(m, d, 16));
  float s = __expf(o0 - m) + __expf(o1 - m) + ((f < 8) ? __expf(o2 - m) : 0.f);
#pragma unroll
  for (int d = 1; d < 16; d <<= 1) s += __shfl_xor(s, d, 16);
  float lse = m + __logf(s);
  float* orow = O + (size_t)i * F3;
  orow[f] = o0 - lse;
  orow[f + 16] = o1 - lse;
  if (f < 8) orow[f + 32] = o2 - lse;
}

// ---------------- launch ----------------

extern "C" void kernel_launch(void* const* d_in, const int* in_sizes, int n_in,
                              void* d_out, int out_size, void* d_ws, size_t ws_size,
                              hipStream_t stream) {
  const float* x  = (const float*)d_in[0];
  const int*   ei = (const int*)d_in[1];
  const float* W1 = (const float*)d_in[2];
  const float* b1 = (const float*)d_in[3];
  const float* W2 = (const float*)d_in[4];
  const float* b2 = (const float*)d_in[5];
  const float* W3 = (const float*)d_in[6];
  const float* b3 = (const float*)d_in[7];
  float* out = (float*)d_out;

  int N = in_sizes[0] / KIN;
  int E = in_sizes[1] / 2;

  char* p = (char*)d_ws;
  auto take = [&](size_t bytes) {
    char* r = p;
    p += (bytes + 255) & ~(size_t)255;
    return r;
  };
  int*   flag  = (int*)take(4);
  int*   cnt   = (int*)take((size_t)N * 4);
  int*   off   = (int*)take((size_t)(N + 1) * 4);
  float* dinv  = (float*)take((size_t)N * 4);
  int*   bsum  = (int*)take(64 * 4);
  int*   carry = (int*)take(64 * 4);
  int*   rank  = (int*)take((size_t)E * 4);
  int2*  ew    = (int2*)take((size_t)E * 8);
  unsigned short* w1t = (unsigned short*)take((size_t)KIN * F1 * 2);
  unsigned short* xb  = (unsigned short*)take((size_t)N * KIN * 2);
  bf16*  h1    = (bf16*)take((size_t)N * F1 * 2);
  bf16*  out1  = (bf16*)take((size_t)N * F1 * 2);
  float* h2    = (float*)take((size_t)N * F2 * 4);
  float* out2  = (float*)take((size_t)N * F2 * 4);

  int nb  = (N + 255) / 256;
  int ebk = (E + 255) / 256;
  int nsc = (N + 1023) / 1024;
  int total8 = (N * KIN) / 8;
  int cvb = (total8 + 255) / 256;
  int tot = ebk + cvb;
  int stride = tot / ebk; if (stride < 1) stride = 1;

  k_init2<<<nb + 128, 256, 0, stream>>>(cnt, ei, flag, W1, w1t, N, nb);
  k_count_conv<<<tot, 256, 0, stream>>>(ei, flag, cnt, rank, E, ebk, stride, x, xb, total8);
  k_scan1<<<nsc, 256, 0, stream>>>(cnt, off, bsum, dinv, N);
  k_scan2<<<1, 64, 0, stream>>>(bsum, carry, nsc);
  k_scan3<<<nsc, 256, 0, stream>>>(off, carry, N);
  k_scatter<<<ebk, 256, 0, stream>>>(ei, flag, off, rank, dinv, ew, E);

  dim3 g1((N + 127) / 128, F1 / 128);
  k_gemm1<<<g1, 256, 0, stream>>>(xb, w1t, h1, N);
  k_agg1<<<(N + 7) / 8, 256, 0, stream>>>(h1, off, ew, dinv, b1, out1, N);
  k_gemm2<<<(N + 15) / 16, 256, 0, stream>>>(out1, W2, h2, N);
  k_agg16<<<(N + 15) / 16, 256, 0, stream>>>(h2, off, ew, dinv, b2, out2, N);
  k_agg3_g3<<<(N + 15) / 16, 256, 0, stream>>>(out2, off, ew, dinv, W3, b3, out, N);
}

// Round 10
// 348.317 us; speedup vs baseline: 1.3859x; 1.0259x over previous
//
#include <hip/hip_runtime.h>
#include <hip/hip_bf16.h>
#include <math.h>

typedef __hip_bfloat16 bf16;
typedef __attribute__((ext_vector_type(8))) __bf16 bf16x8;
typedef __attribute__((ext_vector_type(4))) float f32x4;

#define KIN 512
#define F1  256
#define F2  16
#define F3  40

// ---------------- helpers ----------------

__device__ inline unsigned pk_bf2(float a, float b) {
  bf16 x = __float2bfloat16(a), y = __float2bfloat16(b);
  unsigned short ux = *(unsigned short*)&x, uy = *(unsigned short*)&y;
  return (unsigned)ux | ((unsigned)uy << 16);
}
__device__ inline float bfbits(unsigned u16) {
  unsigned v = u16 << 16;
  return *(float*)&v;
}
__device__ inline void async16(const void* g, void* l) {
  __builtin_amdgcn_global_load_lds((const __attribute__((address_space(1))) void*)g,
                                   (__attribute__((address_space(3))) void*)l, 16, 0, 0);
}
__device__ inline void accum8(float* acc, uint4 h, float w) {
  acc[0] = fmaf(w, bfbits(h.x & 0xffff), acc[0]);
  acc[1] = fmaf(w, bfbits(h.x >> 16),    acc[1]);
  acc[2] = fmaf(w, bfbits(h.y & 0xffff), acc[2]);
  acc[3] = fmaf(w, bfbits(h.y >> 16),    acc[3]);
  acc[4] = fmaf(w, bfbits(h.z & 0xffff), acc[4]);
  acc[5] = fmaf(w, bfbits(h.z >> 16),    acc[5]);
  acc[6] = fmaf(w, bfbits(h.w & 0xffff), acc[6]);
  acc[7] = fmaf(w, bfbits(h.w >> 16),    acc[7]);
}

// ---------------- init: zero cnt + flag + W1 transpose (fused) -------------

__global__ __launch_bounds__(256) void k_init2(int* __restrict__ cnt,
                                               const int* __restrict__ ei, int* __restrict__ flag,
                                               const float* __restrict__ W,
                                               unsigned short* __restrict__ Wt,
                                               int n, int nb) {
  int b = blockIdx.x;
  int t = threadIdx.x;
  if (b < nb) {
    int i = b * 256 + t;
    if (i < n) cnt[i] = 0;
    if (b == 0 && t == 0)
      *flag = (ei[1] == 0 && ei[3] == 0 && ei[5] == 0 && ei[7] == 0) ? 1 : 0;
  } else {
    __shared__ float tile[32][33];
    int b2 = b - nb;
    int k0 = (b2 & 15) * 32;
    int n0 = (b2 >> 4) * 32;
    int lr = t >> 5, lc = t & 31;
#pragma unroll
    for (int rr = 0; rr < 32; rr += 8)
      tile[lr + rr][lc] = W[(size_t)(k0 + lr + rr) * F1 + n0 + lc];
    __syncthreads();
#pragma unroll
    for (int rr = 0; rr < 32; rr += 8) {
      bf16 v = __float2bfloat16(tile[lc][lr + rr]);
      Wt[(size_t)(n0 + lr + rr) * KIN + k0 + lc] = *(unsigned short*)&v;
    }
  }
}

// ---- count (atomic, returns rank) interleaved with x f32->bf16 streaming ---

__global__ __launch_bounds__(256) void k_count_conv(const int* __restrict__ ei,
                                                    const int* __restrict__ flag,
                                                    int* __restrict__ cnt,
                                                    int* __restrict__ rank,
                                                    int E, int nct, int stride,
                                                    const float* __restrict__ X,
                                                    unsigned short* __restrict__ Xb,
                                                    int total8) {
  int b = blockIdx.x;
  int t = threadIdx.x;
  bool is_cnt = (b % stride == 0) && (b / stride < nct);
  if (is_cnt) {
    int e = (b / stride) * 256 + t;
    if (e >= E) return;
    int is64 = *flag;
    int d = is64 ? ei[2 * E + 2 * e] : ei[E + e];
    rank[e] = atomicAdd(&cnt[d], 1);
  } else {
    int nb_before = (b + stride - 1) / stride;
    if (nb_before > nct) nb_before = nct;
    int idx = (b - nb_before) * 256 + t;
    if (idx >= total8) return;
    const float4* src = (const float4*)X + (size_t)idx * 2;
    float4 f0 = src[0], f1 = src[1];
    uint4 pk;
    pk.x = pk_bf2(f0.x, f0.y); pk.y = pk_bf2(f0.z, f0.w);
    pk.z = pk_bf2(f1.x, f1.y); pk.w = pk_bf2(f1.z, f1.w);
    ((uint4*)Xb)[idx] = pk;
  }
}

__global__ __launch_bounds__(256) void k_scan1(const int* __restrict__ cnt,
                                               int* __restrict__ off,
                                               int* __restrict__ bsum,
                                               float* __restrict__ dinv, int N) {
  __shared__ int s[256];
  int t = threadIdx.x;
  int base = blockIdx.x * 1024 + t * 4;
  int v0 = (base + 0 < N) ? cnt[base + 0] : 0;
  int v1 = (base + 1 < N) ? cnt[base + 1] : 0;
  int v2 = (base + 2 < N) ? cnt[base + 2] : 0;
  int v3 = (base + 3 < N) ? cnt[base + 3] : 0;
  if (base + 0 < N) dinv[base + 0] = rsqrtf((float)(v0 + 1));
  if (base + 1 < N) dinv[base + 1] = rsqrtf((float)(v1 + 1));
  if (base + 2 < N) dinv[base + 2] = rsqrtf((float)(v2 + 1));
  if (base + 3 < N) dinv[base + 3] = rsqrtf((float)(v3 + 1));
  int tsum = v0 + v1 + v2 + v3;
  s[t] = tsum;
  __syncthreads();
  for (int d = 1; d < 256; d <<= 1) {
    int u = (t >= d) ? s[t - d] : 0;
    __syncthreads();
    s[t] += u;
    __syncthreads();
  }
  int excl = s[t] - tsum;
  int p0 = excl + v0, p1 = p0 + v1, p2 = p1 + v2, p3 = p2 + v3;
  if (base + 0 < N) off[base + 1] = p0;
  if (base + 1 < N) off[base + 2] = p1;
  if (base + 2 < N) off[base + 3] = p2;
  if (base + 3 < N) off[base + 4] = p3;
  if (t == 255) bsum[blockIdx.x] = s[255];
}

// scan3 with inlined carry reduction (replaces scan2+scan3)
__global__ __launch_bounds__(256) void k_scan3m(int* __restrict__ off,
                                                const int* __restrict__ bsum, int N) {
  __shared__ int cs;
  int t = threadIdx.x;
  if (t < 64) {
    int v = (t < blockIdx.x) ? bsum[t] : 0;   // blockIdx.x <= 49 < 64
    for (int d = 32; d; d >>= 1) v += __shfl_xor(v, d, 64);
    if (t == 0) cs = v;
  }
  __syncthreads();
  int c = cs;
  int base = blockIdx.x * 1024 + t * 4;
#pragma unroll
  for (int k = 0; k < 4; ++k)
    if (base + k < N) off[base + k + 1] += c;
  if (blockIdx.x == 0 && t == 0) off[0] = 0;
}

// ---------------- GEMM1 (m97 structure) + scatter, role-fused dispatch -----

__global__ __launch_bounds__(256) void k_gemm1_sc(const unsigned short* __restrict__ Ab,
                                                  const unsigned short* __restrict__ Bt,
                                                  bf16* __restrict__ C, int M, int ngx,
                                                  const int* __restrict__ ei,
                                                  const int* __restrict__ flag,
                                                  const int* __restrict__ off,
                                                  const int* __restrict__ rank,
                                                  const float* __restrict__ dinv,
                                                  int2* __restrict__ ew, int E) {
  __shared__ unsigned short As[128 * 32];
  __shared__ unsigned short Bs[128 * 32];
  int b = blockIdx.x;
  int t = threadIdx.x;
  int ngemm = ngx * 2;
  if (b >= ngemm) {
    // ---- scatter role (atomic-free) ----
    int e = (b - ngemm) * 256 + t;
    if (e >= E) return;
    int is64 = *flag;
    int s, d;
    if (is64) { s = ei[2 * e]; d = ei[2 * E + 2 * e]; }
    else      { s = ei[e];     d = ei[E + e]; }
    int pos = off[d] + rank[e];
    float w = dinv[s] * dinv[d];
    ew[pos] = make_int2(s, __float_as_int(w));
    return;
  }
  // ---- gemm role ----
  int wave = t >> 6, lane = t & 63;
  int wm = wave >> 1, wn = wave & 1;
  int row0 = (b % ngx) * 128, col0 = (b / ngx) * 128;
  int q = lane >> 4, m16 = lane & 15;
  int srow = lane >> 2, schk = lane & 3;

  f32x4 acc[4][4];
#pragma unroll
  for (int i = 0; i < 4; ++i)
#pragma unroll
    for (int j = 0; j < 4; ++j) acc[i][j] = {0.f, 0.f, 0.f, 0.f};

  for (int kb = 0; kb < 16; ++kb) {
    __syncthreads();
#pragma unroll
    for (int jj = 0; jj < 2; ++jj) {
      int lr = wave * 32 + jj * 16 + srow;
      int gr = row0 + lr; if (gr >= M) gr = M - 1;
      int gchk = schk ^ ((lr >> 1) & 3);
      async16(Ab + (size_t)gr * KIN + kb * 32 + gchk * 8,
              As + (wave * 32 + jj * 16) * 32);
    }
#pragma unroll
    for (int jj = 0; jj < 2; ++jj) {
      int lr = wave * 32 + jj * 16 + srow;
      int gchk = schk ^ ((lr >> 1) & 3);
      async16(Bt + (size_t)(col0 + lr) * KIN + kb * 32 + gchk * 8,
              Bs + (wave * 32 + jj * 16) * 32);
    }
    __syncthreads();
    bf16x8 af[4], bfr[4];
#pragma unroll
    for (int i = 0; i < 4; ++i) {
      int m = wm * 64 + i * 16 + m16;
      af[i] = *(const bf16x8*)(As + m * 32 + ((q ^ ((m >> 1) & 3)) * 8));
    }
#pragma unroll
    for (int j = 0; j < 4; ++j) {
      int n = wn * 64 + j * 16 + m16;
      bfr[j] = *(const bf16x8*)(Bs + n * 32 + ((q ^ ((n >> 1) & 3)) * 8));
    }
#pragma unroll
    for (int j = 0; j < 4; ++j)
#pragma unroll
      for (int i = 0; i < 4; ++i)
        acc[i][j] = __builtin_amdgcn_mfma_f32_16x16x32_bf16(af[i], bfr[j], acc[i][j], 0, 0, 0);
  }

#pragma unroll
  for (int i = 0; i < 4; ++i) {
#pragma unroll
    for (int r = 0; r < 4; ++r) {
      int row = row0 + wm * 64 + i * 16 + q * 4 + r;
      if (row < M) {
#pragma unroll
        for (int j = 0; j < 4; ++j) {
          int col = col0 + wn * 64 + j * 16 + m16;
          C[(size_t)row * F1 + col] = __float2bfloat16(acc[i][j][r]);
        }
      }
    }
  }
}

// ---------------- Aggregation L1, two-phase feature split ------------------
// Phase p = blockIdx >= nbb; each phase aggregates 128 feats for all nodes.
// 16 nodes/block, 16 lanes/node, lane owns 8 feats (16B gathers).
// Per-phase gather working set = 12.8 MB (vs 25.6) -> better L2 hit rate.

__global__ __launch_bounds__(256) void k_agg1(const bf16* __restrict__ H,
                                              const int* __restrict__ off,
                                              const int2* __restrict__ ew,
                                              const float* __restrict__ dinv,
                                              const float* __restrict__ bias,
                                              bf16* __restrict__ O, int N, int nbb) {
  int b = blockIdx.x;
  int t = threadIdx.x;
  int phase = (b >= nbb) ? 1 : 0;
  int b2 = b - phase * nbb;
  int i = b2 * 16 + (t >> 4);
  if (i >= N) return;
  int f0 = phase * 128 + (t & 15) * 8;
  const unsigned short* Hu = (const unsigned short*)H;
  float di = dinv[i];
  float w0 = di * di;
  float acc[8];
  {
    uint4 h = *(const uint4*)(Hu + (size_t)i * F1 + f0);
    acc[0] = w0 * bfbits(h.x & 0xffff); acc[1] = w0 * bfbits(h.x >> 16);
    acc[2] = w0 * bfbits(h.y & 0xffff); acc[3] = w0 * bfbits(h.y >> 16);
    acc[4] = w0 * bfbits(h.z & 0xffff); acc[5] = w0 * bfbits(h.z >> 16);
    acc[6] = w0 * bfbits(h.w & 0xffff); acc[7] = w0 * bfbits(h.w >> 16);
  }
  int e = off[i], e1 = off[i + 1];
  for (; e + 8 <= e1; e += 8) {
    int2 p0 = ew[e + 0], p1 = ew[e + 1], p2 = ew[e + 2], p3 = ew[e + 3];
    int2 p4 = ew[e + 4], p5 = ew[e + 5], p6 = ew[e + 6], p7 = ew[e + 7];
    uint4 g0 = *(const uint4*)(Hu + (size_t)p0.x * F1 + f0);
    uint4 g1 = *(const uint4*)(Hu + (size_t)p1.x * F1 + f0);
    uint4 g2 = *(const uint4*)(Hu + (size_t)p2.x * F1 + f0);
    uint4 g3 = *(const uint4*)(Hu + (size_t)p3.x * F1 + f0);
    uint4 g4 = *(const uint4*)(Hu + (size_t)p4.x * F1 + f0);
    uint4 g5 = *(const uint4*)(Hu + (size_t)p5.x * F1 + f0);
    uint4 g6 = *(const uint4*)(Hu + (size_t)p6.x * F1 + f0);
    uint4 g7 = *(const uint4*)(Hu + (size_t)p7.x * F1 + f0);
    accum8(acc, g0, __int_as_float(p0.y));
    accum8(acc, g1, __int_as_float(p1.y));
    accum8(acc, g2, __int_as_float(p2.y));
    accum8(acc, g3, __int_as_float(p3.y));
    accum8(acc, g4, __int_as_float(p4.y));
    accum8(acc, g5, __int_as_float(p5.y));
    accum8(acc, g6, __int_as_float(p6.y));
    accum8(acc, g7, __int_as_float(p7.y));
  }
  for (; e < e1; ++e) {
    int2 pe = ew[e];
    uint4 g = *(const uint4*)(Hu + (size_t)pe.x * F1 + f0);
    accum8(acc, g, __int_as_float(pe.y));
  }
  float4 b0 = *(const float4*)(bias + f0);
  float4 b1 = *(const float4*)(bias + f0 + 4);
  float bb[8] = {b0.x, b0.y, b0.z, b0.w, b1.x, b1.y, b1.z, b1.w};
  uint4 o;
  unsigned* op = (unsigned*)&o;
#pragma unroll
  for (int k = 0; k < 4; ++k) {
    float lo = fmaxf(acc[2 * k] + bb[2 * k], 0.f);
    float hi = fmaxf(acc[2 * k + 1] + bb[2 * k + 1], 0.f);
    op[k] = pk_bf2(lo, hi);
  }
  *(uint4*)((unsigned short*)O + (size_t)i * F1 + f0) = o;
}

// ---------------- GEMM2: h2 = out1 @ W2 (bf16 in, f32 out) ----------------

__global__ __launch_bounds__(256) void k_gemm2(const bf16* __restrict__ A,
                                               const float* __restrict__ W,
                                               float* __restrict__ C, int N) {
  __shared__ float Ws[F1 * F2];
  __shared__ float Ts[16][F1];
  int t = threadIdx.x;
  int r0 = blockIdx.x * 16;
#pragma unroll
  for (int j = 0; j < 16; ++j) Ws[t + 256 * j] = W[t + 256 * j];
  const unsigned short* Au = (const unsigned short*)A;
#pragma unroll
  for (int j = 0; j < 2; ++j) {
    int idx = t + 256 * j;
    int r = idx >> 5;
    int c8 = (idx & 31) * 8;
    int row = r0 + r;
    uint4 g = make_uint4(0, 0, 0, 0);
    if (row < N) g = *(const uint4*)(Au + (size_t)row * F1 + c8);
    float* ts = &Ts[r][c8];
    ts[0] = bfbits(g.x & 0xffff); ts[1] = bfbits(g.x >> 16);
    ts[2] = bfbits(g.y & 0xffff); ts[3] = bfbits(g.y >> 16);
    ts[4] = bfbits(g.z & 0xffff); ts[5] = bfbits(g.z >> 16);
    ts[6] = bfbits(g.w & 0xffff); ts[7] = bfbits(g.w >> 16);
  }
  __syncthreads();
  int r = t >> 4, c = t & 15;
  float acc = 0.f;
  const float4* tv = (const float4*)&Ts[r][0];
#pragma unroll 8
  for (int k4 = 0; k4 < 64; ++k4) {
    float4 a = tv[k4];
    int k = k4 * 4;
    acc = fmaf(a.x, Ws[(k + 0) * 16 + c], acc);
    acc = fmaf(a.y, Ws[(k + 1) * 16 + c], acc);
    acc = fmaf(a.z, Ws[(k + 2) * 16 + c], acc);
    acc = fmaf(a.w, Ws[(k + 3) * 16 + c], acc);
  }
  int row = r0 + r;
  if (row < N) C[(size_t)row * F2 + c] = acc;
}

// ---------------- Aggregation, 16 features (layer 2) ----------------

__global__ __launch_bounds__(256) void k_agg16(const float* __restrict__ H,
                                               const int* __restrict__ off,
                                               const int2* __restrict__ ew,
                                               const float* __restrict__ dinv,
                                               const float* __restrict__ bias,
                                               float* __restrict__ O, int N) {
  int t = threadIdx.x;
  int i = blockIdx.x * 16 + (t >> 4);
  int f = t & 15;
  if (i >= N) return;
  float di = dinv[i];
  float acc = di * di * H[(size_t)i * F2 + f];
  int e = off[i], e1 = off[i + 1];
  for (; e + 4 <= e1; e += 4) {
    int2 p0 = ew[e + 0], p1 = ew[e + 1], p2 = ew[e + 2], p3 = ew[e + 3];
    float g0 = H[(size_t)p0.x * F2 + f];
    float g1 = H[(size_t)p1.x * F2 + f];
    float g2 = H[(size_t)p2.x * F2 + f];
    float g3 = H[(size_t)p3.x * F2 + f];
    acc = fmaf(__int_as_float(p0.y), g0, acc);
    acc = fmaf(__int_as_float(p1.y), g1, acc);
    acc = fmaf(__int_as_float(p2.y), g2, acc);
    acc = fmaf(__int_as_float(p3.y), g3, acc);
  }
  for (; e < e1; ++e) {
    int2 pe = ew[e];
    acc = fmaf(__int_as_float(pe.y), H[(size_t)pe.x * F2 + f], acc);
  }
  acc = fmaxf(acc + bias[f], 0.f);
  O[(size_t)i * F2 + f] = acc;
}

// ---------------- agg(out2) + GEMM3 + bias + log_softmax fused -------------

__global__ __launch_bounds__(256) void k_agg3_g3(const float* __restrict__ H,
                                                 const int* __restrict__ off,
                                                 const int2* __restrict__ ew,
                                                 const float* __restrict__ dinv,
                                                 const float* __restrict__ W3,
                                                 const float* __restrict__ b3,
                                                 float* __restrict__ O, int N) {
  __shared__ float W3s[F2 * F3];
  __shared__ float b3s[F3];
  __shared__ float aggs[16 * 17];
  int t = threadIdx.x;
  for (int idx = t; idx < F2 * F3; idx += 256) W3s[idx] = W3[idx];
  if (t < F3) b3s[t] = b3[t];
  __syncthreads();

  int node = t >> 4, f = t & 15;
  int i = blockIdx.x * 16 + node;
  if (i >= N) return;
  float di = dinv[i];
  float acc = di * di * H[(size_t)i * F2 + f];
  int e = off[i], e1 = off[i + 1];
  for (; e + 4 <= e1; e += 4) {
    int2 p0 = ew[e + 0], p1 = ew[e + 1], p2 = ew[e + 2], p3 = ew[e + 3];
    float g0 = H[(size_t)p0.x * F2 + f];
    float g1 = H[(size_t)p1.x * F2 + f];
    float g2 = H[(size_t)p2.x * F2 + f];
    float g3 = H[(size_t)p3.x * F2 + f];
    acc = fmaf(__int_as_float(p0.y), g0, acc);
    acc = fmaf(__int_as_float(p1.y), g1, acc);
    acc = fmaf(__int_as_float(p2.y), g2, acc);
    acc = fmaf(__int_as_float(p3.y), g3, acc);
  }
  for (; e < e1; ++e) {
    int2 pe = ew[e];
    acc = fmaf(__int_as_float(pe.y), H[(size_t)pe.x * F2 + f], acc);
  }
  aggs[node * 17 + f] = acc;

  const float* ar = &aggs[node * 17];
  float o0 = b3s[f], o1 = b3s[f + 16], o2 = (f < 8) ? b3s[f + 32] : 0.f;
#pragma unroll
  for (int k = 0; k < F2; ++k) {
    float a = ar[k];
    o0 = fmaf(a, W3s[k * F3 + f], o0);
    o1 = fmaf(a, W3s[k * F3 + f + 16], o1);
    if (f < 8) o2 = fmaf(a, W3s[k * F3 + f + 32], o2);
  }
  float m = fmaxf(o0, o1);
  if (f < 8) m = fmaxf(m, o2);
#pragma unroll
  for (int d = 1; d < 16; d <<= 1) m = fmaxf(m, __shfl_xor(m, d, 16));
  float s = __expf(o0 - m) + __expf(o1 - m) + ((f < 8) ? __expf(o2 - m) : 0.f);
#pragma unroll
  for (int d = 1; d < 16; d <<= 1) s += __shfl_xor(s, d, 16);
  float lse = m + __logf(s);
  float* orow = O + (size_t)i * F3;
  orow[f] = o0 - lse;
  orow[f + 16] = o1 - lse;
  if (f < 8) orow[f + 32] = o2 - lse;
}

// ---------------- launch ----------------

extern "C" void kernel_launch(void* const* d_in, const int* in_sizes, int n_in,
                              void* d_out, int out_size, void* d_ws, size_t ws_size,
                              hipStream_t stream) {
  const float* x  = (const float*)d_in[0];
  const int*   ei = (const int*)d_in[1];
  const float* W1 = (const float*)d_in[2];
  const float* b1 = (const float*)d_in[3];
  const float* W2 = (const float*)d_in[4];
  const float* b2 = (const float*)d_in[5];
  const float* W3 = (const float*)d_in[6];
  const float* b3 = (const float*)d_in[7];
  float* out = (float*)d_out;

  int N = in_sizes[0] / KIN;
  int E = in_sizes[1] / 2;

  char* p = (char*)d_ws;
  auto take = [&](size_t bytes) {
    char* r = p;
    p += (bytes + 255) & ~(size_t)255;
    return r;
  };
  int*   flag  = (int*)take(4);
  int*   cnt   = (int*)take((size_t)N * 4);
  int*   off   = (int*)take((size_t)(N + 1) * 4);
  float* dinv  = (float*)take((size_t)N * 4);
  int*   bsum  = (int*)take(64 * 4);
  int*   rank  = (int*)take((size_t)E * 4);
  int2*  ew    = (int2*)take((size_t)E * 8);
  unsigned short* w1t = (unsigned short*)take((size_t)KIN * F1 * 2);
  unsigned short* xb  = (unsigned short*)take((size_t)N * KIN * 2);
  bf16*  h1    = (bf16*)take((size_t)N * F1 * 2);
  bf16*  out1  = (bf16*)take((size_t)N * F1 * 2);
  float* h2    = (float*)take((size_t)N * F2 * 4);
  float* out2  = (float*)take((size_t)N * F2 * 4);

  int nb  = (N + 255) / 256;
  int ebk = (E + 255) / 256;
  int nsc = (N + 1023) / 1024;
  int total8 = (N * KIN) / 8;
  int cvb = (total8 + 255) / 256;
  int tot = ebk + cvb;
  int stride = tot / ebk; if (stride < 1) stride = 1;

  k_init2<<<nb + 128, 256, 0, stream>>>(cnt, ei, flag, W1, w1t, N, nb);
  k_count_conv<<<tot, 256, 0, stream>>>(ei, flag, cnt, rank, E, ebk, stride, x, xb, total8);
  k_scan1<<<nsc, 256, 0, stream>>>(cnt, off, bsum, dinv, N);
  k_scan3m<<<nsc, 256, 0, stream>>>(off, bsum, N);

  int ngx = (N + 127) / 128;
  k_gemm1_sc<<<ngx * 2 + ebk, 256, 0, stream>>>(xb, w1t, h1, N, ngx,
                                                ei, flag, off, rank, dinv, ew, E);

  int nbb = (N + 15) / 16;
  k_agg1<<<nbb * 2, 256, 0, stream>>>(h1, off, ew, dinv, b1, out1, N, nbb);
  k_gemm2<<<(N + 15) / 16, 256, 0, stream>>>(out1, W2, h2, N);
  k_agg16<<<(N + 15) / 16, 256, 0, stream>>>(h2, off, ew, dinv, b2, out2, N);
  k_agg3_g3<<<(N + 15) / 16, 256, 0, stream>>>(out2, off, ew, dinv, W3, b3, out, N);
}